// Round 1
// baseline (1992.844 us; speedup 1.0000x reference)
//
#include <hip/hip_runtime.h>
#include <hip/hip_bf16.h>
#include <math.h>

#define N_NODES 16384
#define DIMV 1024
#define NHEADS 16
#define HEADD 64

// ---------- helpers ----------

__device__ __forceinline__ float waveReduceSum(float v) {
#pragma unroll
  for (int m = 32; m; m >>= 1) v += __shfl_xor(v, m);
  return v;
}

__device__ __forceinline__ float blockReduceSum(float v, float* red) {
  float w = waveReduceSum(v);
  __syncthreads();
  if ((threadIdx.x & 63) == 0) red[threadIdx.x >> 6] = w;
  __syncthreads();
  return red[0] + red[1] + red[2] + red[3];
}

__device__ __forceinline__ float elup1(float z) {
  // jax.nn.elu(z) + 1
  return z > 0.0f ? z + 1.0f : expm1f(z) + 1.0f;
}

__device__ __forceinline__ float clampabs(float x, float eps) {
  // s = sign(sign(x)+0.5): +1 for x>=0, -1 for x<0
  float s = (x >= 0.0f) ? 1.0f : -1.0f;
  return s * fmaxf(fabsf(x), eps);
}

// ---------- fp32 tiled GEMM: C[M x 1024] = A[M x 1024] @ B[1024 x 1024] (+ bias) ----------
// BM=BN=128, BK=8, 256 threads, 8x8 per thread.

__global__ __launch_bounds__(256) void gemm128(const float* __restrict__ A,
                                               const float* __restrict__ B,
                                               const float* __restrict__ bias,
                                               float* __restrict__ C) {
  __shared__ float As[8][128];
  __shared__ float Bs[8][128];
  const int t = threadIdx.x;
  const int bm = blockIdx.y * 128;
  const int bn = blockIdx.x * 128;
  const int tm = (t >> 4) * 8;
  const int tn = (t & 15) * 8;
  const int arow = t >> 1, acol = (t & 1) * 4;   // A tile 128 rows x 8 k
  const int brow = t >> 5, bcol = (t & 31) * 4;  // B tile 8 k x 128 cols
  const float* Ap = A + (size_t)(bm + arow) * DIMV + acol;
  const float* Bp = B + (size_t)brow * DIMV + bn + bcol;

  float acc[8][8];
#pragma unroll
  for (int i = 0; i < 8; ++i)
#pragma unroll
    for (int j = 0; j < 8; ++j) acc[i][j] = 0.0f;

  for (int k0 = 0; k0 < DIMV; k0 += 8) {
    float4 a4 = *(const float4*)(Ap + k0);
    float4 b4 = *(const float4*)(Bp + (size_t)k0 * DIMV);
    As[acol + 0][arow] = a4.x;
    As[acol + 1][arow] = a4.y;
    As[acol + 2][arow] = a4.z;
    As[acol + 3][arow] = a4.w;
    *(float4*)&Bs[brow][bcol] = b4;
    __syncthreads();
#pragma unroll
    for (int k = 0; k < 8; ++k) {
      float a[8], b[8];
#pragma unroll
      for (int i = 0; i < 8; ++i) a[i] = As[k][tm + i];
#pragma unroll
      for (int j = 0; j < 8; ++j) b[j] = Bs[k][tn + j];
#pragma unroll
      for (int i = 0; i < 8; ++i)
#pragma unroll
        for (int j = 0; j < 8; ++j) acc[i][j] = fmaf(a[i], b[j], acc[i][j]);
    }
    __syncthreads();
  }

  float bv[8];
#pragma unroll
  for (int j = 0; j < 8; ++j) bv[j] = bias ? bias[bn + tn + j] : 0.0f;
#pragma unroll
  for (int i = 0; i < 8; ++i) {
    float4 r0 = make_float4(acc[i][0] + bv[0], acc[i][1] + bv[1],
                            acc[i][2] + bv[2], acc[i][3] + bv[3]);
    float4 r1 = make_float4(acc[i][4] + bv[4], acc[i][5] + bv[5],
                            acc[i][6] + bv[6], acc[i][7] + bv[7]);
    float* cp = C + (size_t)(bm + tm + i) * DIMV + bn + tn;
    *(float4*)cp = r0;
    *(float4*)(cp + 4) = r1;
  }
}

// ---------- row transform: mobius_matvec tail + kappa_relu, optional per-head denom ----------
// One block (256 thr) per row; thread t owns float4 at elements 4t..4t+3.
// res = tanh(mxn/xn * atanh(clip(xn))) * mx / mxn   (mobius_matvec, xn from xsrc row)
// then kappa_relu: u = atanh(clip(|res|_2))/|res|_2 * res; u=relu(u);
//                  out = project(tanh(|u|)*u/|u|)
// if denom != null: denom[h*N + row] = max(1 - sum_head(out^2), 1e-15)

__global__ __launch_bounds__(256) void rowtrans_kernel(const float* __restrict__ xsrc,
                                                       const float* __restrict__ msrc,
                                                       float* __restrict__ dst,
                                                       float* __restrict__ denom) {
  __shared__ float red[4];
  __shared__ float orow[DIMV];
  const int row = blockIdx.x;
  const int t = threadIdx.x;
  float4 x4 = ((const float4*)(xsrc + (size_t)row * DIMV))[t];
  float4 m4 = ((const float4*)(msrc + (size_t)row * DIMV))[t];
  float sx = x4.x * x4.x + x4.y * x4.y + x4.z * x4.z + x4.w * x4.w;
  float sm = m4.x * m4.x + m4.y * m4.y + m4.z * m4.z + m4.w * m4.w;
  sx = blockReduceSum(sx, red);
  sm = blockReduceSum(sm, red);

  float xn = fmaxf(sqrtf(sx), 1e-15f);
  float mxn = fmaxf(sqrtf(sm), 1e-15f);
  float cx = fminf(xn, 1.0f - 1e-7f);
  float t1 = tanhf(mxn / xn * atanhf(cx));  // >= 0
  float s1 = t1 / mxn;                      // res = s1 * m

  float yn = fmaxf(fabsf(t1), 1e-15f);      // ||res||
  float a = atanhf(fminf(yn, 1.0f - 1e-7f)) / yn;
  float k1 = a * s1;                        // u_pre = k1 * m
  float4 u = make_float4(fmaxf(k1 * m4.x, 0.0f), fmaxf(k1 * m4.y, 0.0f),
                         fmaxf(k1 * m4.z, 0.0f), fmaxf(k1 * m4.w, 0.0f));
  float su = u.x * u.x + u.y * u.y + u.z * u.z + u.w * u.w;
  su = blockReduceSum(su, red);

  float un = fmaxf(sqrtf(su), 1e-15f);
  float t2 = tanhf(un);  // ||out_pre|| = t2 >= 0
  float s2 = t2 / un;
  if (t2 > 0.996f) s2 *= 0.996f / t2;  // project
  float4 o = make_float4(s2 * u.x, s2 * u.y, s2 * u.z, s2 * u.w);
  ((float4*)(dst + (size_t)row * DIMV))[t] = o;

  if (denom) {
    ((float4*)orow)[t] = o;
    __syncthreads();
    if (t < NHEADS) {
      float s = 0.0f;
#pragma unroll
      for (int i = 0; i < HEADD; ++i) {
        float v = orow[t * HEADD + i];
        s = fmaf(v, v, s);
      }
      denom[t * N_NODES + row] = fmaxf(1.0f - s, 1e-15f);
    }
  }
}

// ---------- v2: in-place K -> denominator*(elu(K/denom_pt)+1)*mask; accumulate v2_sum ----------
// Block handles 64 rows; thread t owns cols 4t..4t+3 (head h = t>>4).

__global__ __launch_bounds__(256) void v2_kernel(float* __restrict__ kbuf,
                                                 const float* __restrict__ denom,
                                                 const float* __restrict__ mask,
                                                 float* __restrict__ v2sum) {
  const int t = threadIdx.x;
  const int c0 = t * 4;
  const int h = t >> 4;
  const int row0 = blockIdx.x * 64;
  float a0 = 0, a1 = 0, a2 = 0, a3 = 0;
  for (int r = 0; r < 64; ++r) {
    const int row = row0 + r;
    const float dp = denom[h * N_NODES + row];
    const float gamma = 2.0f / dp;
    const float den = clampabs(gamma - 1.0f, 1e-10f);
    const float mk = mask[row];
    const float invdp = 1.0f / dp;
    float4 kv = *(const float4*)(kbuf + (size_t)row * DIMV + c0);
    float4 v;
    v.x = den * elup1(kv.x * invdp) * mk;
    v.y = den * elup1(kv.y * invdp) * mk;
    v.z = den * elup1(kv.z * invdp) * mk;
    v.w = den * elup1(kv.w * invdp) * mk;
    *(float4*)(kbuf + (size_t)row * DIMV + c0) = v;
    a0 += v.x; a1 += v.y; a2 += v.z; a3 += v.w;
  }
  atomicAdd(&v2sum[c0 + 0], a0);
  atomicAdd(&v2sum[c0 + 1], a1);
  atomicAdd(&v2sum[c0 + 2], a2);
  atomicAdd(&v2sum[c0 + 3], a3);
}

// ---------- context[h][d][e] = sum_n v2[h,n,d] * (gamma/denominator * mask * V)[h,n,e] ----------
// grid (16 row-chunks of 1024, 16 heads); 256 threads, 4x4 per thread; atomics into zeroed ctx.

__global__ __launch_bounds__(256) void context_kernel(const float* __restrict__ v2buf,
                                                      const float* __restrict__ vbuf,
                                                      const float* __restrict__ denom,
                                                      const float* __restrict__ mask,
                                                      float* __restrict__ ctx) {
  __shared__ float s2[64][65];
  __shared__ float sx[64][65];
  const int h = blockIdx.y;
  const int t = threadIdx.x;
  const int d0 = (t >> 4) * 4;
  const int e0 = (t & 15) * 4;
  float acc[4][4];
#pragma unroll
  for (int i = 0; i < 4; ++i)
#pragma unroll
    for (int j = 0; j < 4; ++j) acc[i][j] = 0.0f;

  const int rbase = blockIdx.x * 1024;
  for (int c = 0; c < 16; ++c) {
#pragma unroll
    for (int i = 0; i < 4; ++i) {
      int f = i * 256 + t;
      int r = f >> 4;
      int cc = (f & 15) * 4;
      int row = rbase + c * 64 + r;
      float4 a = *(const float4*)(v2buf + (size_t)row * DIMV + h * HEADD + cc);
      s2[r][cc + 0] = a.x; s2[r][cc + 1] = a.y; s2[r][cc + 2] = a.z; s2[r][cc + 3] = a.w;
      float dp = denom[h * N_NODES + row];
      float gamma = 2.0f / dp;
      float den = clampabs(gamma - 1.0f, 1e-10f);
      float c1 = gamma / den * mask[row];
      float4 b = *(const float4*)(vbuf + (size_t)row * DIMV + h * HEADD + cc);
      sx[r][cc + 0] = c1 * b.x; sx[r][cc + 1] = c1 * b.y;
      sx[r][cc + 2] = c1 * b.z; sx[r][cc + 3] = c1 * b.w;
    }
    __syncthreads();
    for (int r = 0; r < 64; ++r) {
      float av[4], bv[4];
#pragma unroll
      for (int i = 0; i < 4; ++i) av[i] = s2[r][d0 + i];
#pragma unroll
      for (int j = 0; j < 4; ++j) bv[j] = sx[r][e0 + j];
#pragma unroll
      for (int i = 0; i < 4; ++i)
#pragma unroll
        for (int j = 0; j < 4; ++j) acc[i][j] = fmaf(av[i], bv[j], acc[i][j]);
    }
    __syncthreads();
  }
#pragma unroll
  for (int i = 0; i < 4; ++i)
#pragma unroll
    for (int j = 0; j < 4; ++j)
      atomicAdd(&ctx[h * 4096 + (d0 + i) * 64 + (e0 + j)], acc[i][j]);
}

// ---------- out: v1 = elu(Q/dp)+1; D = v1.v2sum; out = (v1@ctx)*Dinv; project; mobius*0.5; project ----------
// In-place into qbuf (comb). grid (256 n-chunks of 64, 16 heads); 4 waves/block, 1 (h,n) per wave-iter.

__global__ __launch_bounds__(256) void out_kernel(float* __restrict__ qbuf,
                                                  const float* __restrict__ denom,
                                                  const float* __restrict__ v2sum,
                                                  const float* __restrict__ ctx) {
  __shared__ float sctx[64][65];
  __shared__ float sv2s[64];
  const int h = blockIdx.y;
  const int t = threadIdx.x;
#pragma unroll
  for (int i = 0; i < 4; ++i) {
    int f = i * 256 + t;
    int r = f >> 4;
    int cc = (f & 15) * 4;
    float4 v = *(const float4*)(ctx + h * 4096 + r * 64 + cc);
    sctx[r][cc + 0] = v.x; sctx[r][cc + 1] = v.y; sctx[r][cc + 2] = v.z; sctx[r][cc + 3] = v.w;
  }
  if (t < HEADD) sv2s[t] = v2sum[h * HEADD + t];
  __syncthreads();

  const int wave = t >> 6;
  const int lane = t & 63;
  for (int it = 0; it < 16; ++it) {
    const int n = blockIdx.x * 64 + it * 4 + wave;
    const float dp = denom[h * N_NODES + n];
    const float q = qbuf[(size_t)n * DIMV + h * HEADD + lane];
    const float v1 = elup1(q / dp);
    float D = waveReduceSum(v1 * sv2s[lane]);
    const float Dinv = 1.0f / (D == 0.0f ? 1e-5f : D);
    float o = 0.0f;
#pragma unroll
    for (int d = 0; d < 64; ++d) {
      float v1d = __shfl(v1, d);
      o = fmaf(v1d, sctx[d][lane], o);
    }
    o *= Dinv;
    // project
    float s = waveReduceSum(o * o);
    float n1 = fmaxf(sqrtf(s), 1e-15f);
    if (n1 > 0.996f) o *= 0.996f / n1;
    // mobius_scalar_mul(0.5, ., k)
    float xn = fmaxf(fminf(n1, 0.996f), 1e-15f);
    float cx = fminf(xn, 1.0f - 1e-7f);
    float t2 = tanhf(0.5f * atanhf(cx));  // >= 0
    o *= t2 / xn;
    // project (norm is t2)
    if (t2 > 0.996f) o *= 0.996f / t2;
    qbuf[(size_t)n * DIMV + h * HEADD + lane] = o;
  }
}

// ---------- launch ----------

extern "C" void kernel_launch(void* const* d_in, const int* in_sizes, int n_in,
                              void* d_out, int out_size, void* d_ws, size_t ws_size,
                              hipStream_t stream) {
  const float* X = (const float*)d_in[0];
  const float* mask = (const float*)d_in[1];
  const float* Wq = (const float*)d_in[2];
  const float* bq = (const float*)d_in[3];
  const float* Wk = (const float*)d_in[4];
  const float* bk = (const float*)d_in[5];
  const float* Wv = (const float*)d_in[6];
  const float* Wff = (const float*)d_in[7];
  float* out = (float*)d_out;

  const size_t MAT = (size_t)N_NODES * DIMV;  // 16777216 floats
  float* bufQ = (float*)d_ws;                 // Q, then comb (in-place)
  float* bufK = bufQ + MAT;                   // K, then v2 (in-place)
  float* bufV = bufK + MAT;                   // X@Wv, then V (in-place)
  float* denom = bufV + MAT;                  // [16][16384]
  float* v2sum = denom + (size_t)NHEADS * N_NODES;  // [1024]
  float* ctx = v2sum + 1024;                  // [16][64][64]
  const size_t need = (3 * MAT + (size_t)NHEADS * N_NODES + 1024 + 4096 * NHEADS) * sizeof(float);
  if (ws_size < need) return;  // workspace too small: fail loudly (poisoned output)

  dim3 ggrid(DIMV / 128, N_NODES / 128);

  // V path
  gemm128<<<ggrid, 256, 0, stream>>>(X, Wv, nullptr, bufV);
  rowtrans_kernel<<<N_NODES, 256, 0, stream>>>(X, bufV, bufV, denom);
  // K path -> v2, v2_sum
  gemm128<<<ggrid, 256, 0, stream>>>(X, Wk, bk, bufK);
  hipMemsetAsync(v2sum, 0, (1024 + 4096 * NHEADS) * sizeof(float), stream);
  v2_kernel<<<N_NODES / 64, 256, 0, stream>>>(bufK, denom, mask, v2sum);
  // context
  context_kernel<<<dim3(16, NHEADS), 256, 0, stream>>>(bufK, bufV, denom, mask, ctx);
  // Q path -> attention out (in-place into bufQ = comb)
  gemm128<<<ggrid, 256, 0, stream>>>(X, Wq, bq, bufQ);
  out_kernel<<<dim3(N_NODES / 64, NHEADS), 256, 0, stream>>>(bufQ, denom, v2sum, ctx);
  // final: mobius_matvec(Wff, comb) + kappa_relu -> d_out
  gemm128<<<ggrid, 256, 0, stream>>>(bufQ, Wff, nullptr, out);
  rowtrans_kernel<<<N_NODES, 256, 0, stream>>>(bufQ, out, out, nullptr);
}

// Round 2
// 1060.858 us; speedup vs baseline: 1.8785x; 1.8785x over previous
//
#include <hip/hip_runtime.h>
#include <hip/hip_bf16.h>
#include <math.h>

#define N_NODES 16384
#define DIMV 1024
#define NHEADS 16
#define HEADD 64

typedef __attribute__((ext_vector_type(8))) short short8;
typedef __attribute__((ext_vector_type(4))) float f32x4;

// ---------- helpers ----------

__device__ __forceinline__ float waveReduceSum(float v) {
#pragma unroll
  for (int m = 32; m; m >>= 1) v += __shfl_xor(v, m);
  return v;
}

__device__ __forceinline__ float blockReduceSum(float v, float* red) {
  float w = waveReduceSum(v);
  __syncthreads();
  if ((threadIdx.x & 63) == 0) red[threadIdx.x >> 6] = w;
  __syncthreads();
  return red[0] + red[1] + red[2] + red[3];
}

__device__ __forceinline__ float elup1(float z) {
  return z > 0.0f ? z + 1.0f : expm1f(z) + 1.0f;
}

__device__ __forceinline__ float clampabs(float x, float eps) {
  float s = (x >= 0.0f) ? 1.0f : -1.0f;
  return s * fmaxf(fabsf(x), eps);
}

// fp32 -> bf16 bits, round-to-nearest-even (values are finite/small; no NaN path)
__device__ __forceinline__ unsigned short f2b(float x) {
  unsigned u = __float_as_uint(x);
  unsigned r = (u + 0x7FFFu + ((u >> 16) & 1u)) >> 16;
  return (unsigned short)r;
}
__device__ __forceinline__ float b2f(unsigned short h) {
  return __uint_as_float(((unsigned)h) << 16);
}
// mode 0: bf16(x); mode 1: bf16(x - float(bf16(x)))  (low part for split GEMM)
template <int MODE>
__device__ __forceinline__ unsigned short f2b_m(float x) {
  if (MODE == 0) return f2b(x);
  return f2b(x - b2f(f2b(x)));
}

// ---------- weight transpose: Wt[n][k] = W[k][n], 1024x1024 ----------
__global__ __launch_bounds__(256) void transpose1024(const float* __restrict__ src,
                                                     float* __restrict__ dst) {
  __shared__ float tile[32][33];
  const int bx = blockIdx.x * 32, by = blockIdx.y * 32;
  const int tx = threadIdx.x & 31, ty = threadIdx.x >> 5;  // 32 x 8
#pragma unroll
  for (int i = 0; i < 32; i += 8) tile[ty + i][tx] = src[(size_t)(by + ty + i) * DIMV + bx + tx];
  __syncthreads();
#pragma unroll
  for (int i = 0; i < 32; i += 8) dst[(size_t)(bx + ty + i) * DIMV + by + tx] = tile[tx][ty + i];
}

// ---------- bf16 MFMA GEMM: C[M x 1024] (+)= bf16(A) @ bf16(Bt^T) (+ bias) ----------
// A: [M][1024] fp32 (k-contiguous). Bt: [1024 n][1024 k] fp32 (k-contiguous, pre-transposed).
// 128x128 tile, BK=32, 256 threads = 4 waves (2x2), each wave 64x64 = 4x4 frags of 16x16x32.
// Staging converts fp32->bf16 in registers (AMODE/BMODE: 0=hi, 1=lo residual).

template <int AMODE, int BMODE, bool ACCUM, bool BIAS>
__global__ __launch_bounds__(256) void gemm_mfma(const float* __restrict__ A,
                                                 const float* __restrict__ Bt,
                                                 const float* __restrict__ bias,
                                                 float* __restrict__ C) {
  __shared__ unsigned short As[128][32];
  __shared__ unsigned short Bs[128][32];
  const int t = threadIdx.x;
  const int bm = blockIdx.y * 128;
  const int bn = blockIdx.x * 128;
  const int w = t >> 6, lane = t & 63;
  const int wr = (w >> 1) * 64, wc = (w & 1) * 64;
  // staging: 1024 quads/tile, 4 per thread: row = (t>>3)+32i, kq = (t&7)*4
  const int srow = t >> 3;
  const int skq = (t & 7) * 4;
  const int l15 = lane & 15;
  const int kk = (lane >> 4) * 8;  // k-base of this lane's fragment

  f32x4 acc[4][4];
#pragma unroll
  for (int i = 0; i < 4; ++i)
#pragma unroll
    for (int j = 0; j < 4; ++j) acc[i][j] = (f32x4){0.f, 0.f, 0.f, 0.f};

  for (int k0 = 0; k0 < DIMV; k0 += 32) {
#pragma unroll
    for (int i = 0; i < 4; ++i) {
      const int row = srow + 32 * i;
      float4 av = *(const float4*)(A + (size_t)(bm + row) * DIMV + k0 + skq);
      float4 bv = *(const float4*)(Bt + (size_t)(bn + row) * DIMV + k0 + skq);
      unsigned short ah[4] = {f2b_m<AMODE>(av.x), f2b_m<AMODE>(av.y),
                              f2b_m<AMODE>(av.z), f2b_m<AMODE>(av.w)};
      unsigned short bh[4] = {f2b_m<BMODE>(bv.x), f2b_m<BMODE>(bv.y),
                              f2b_m<BMODE>(bv.z), f2b_m<BMODE>(bv.w)};
      *(uint2*)&As[row][skq] = *(uint2*)ah;
      *(uint2*)&Bs[row][skq] = *(uint2*)bh;
    }
    __syncthreads();
    short8 af[4], bf[4];
#pragma unroll
    for (int i = 0; i < 4; ++i) af[i] = *(const short8*)&As[wr + i * 16 + l15][kk];
#pragma unroll
    for (int j = 0; j < 4; ++j) bf[j] = *(const short8*)&Bs[wc + j * 16 + l15][kk];
#pragma unroll
    for (int i = 0; i < 4; ++i)
#pragma unroll
      for (int j = 0; j < 4; ++j)
        acc[i][j] = __builtin_amdgcn_mfma_f32_16x16x32_bf16(af[i], bf[j], acc[i][j], 0, 0, 0);
    __syncthreads();
  }

  // C/D layout: col = lane&15, row = (lane>>4)*4 + r   [m89/m91 verified]
  const int rbase = (lane >> 4) * 4;
#pragma unroll
  for (int j = 0; j < 4; ++j) {
    const int col = bn + wc + j * 16 + l15;
    float bb = BIAS ? bias[col] : 0.0f;
#pragma unroll
    for (int i = 0; i < 4; ++i) {
#pragma unroll
      for (int r = 0; r < 4; ++r) {
        const int row = bm + wr + i * 16 + rbase + r;
        float v = acc[i][j][r] + bb;
        if (ACCUM)
          C[(size_t)row * DIMV + col] += v;
        else
          C[(size_t)row * DIMV + col] = v;
      }
    }
  }
}

// ---------- row transform: mobius_matvec tail + kappa_relu, optional per-head denom ----------
__global__ __launch_bounds__(256) void rowtrans_kernel(const float* __restrict__ xsrc,
                                                       const float* __restrict__ msrc,
                                                       float* __restrict__ dst,
                                                       float* __restrict__ denom) {
  __shared__ float red[4];
  __shared__ float orow[DIMV];
  const int row = blockIdx.x;
  const int t = threadIdx.x;
  float4 x4 = ((const float4*)(xsrc + (size_t)row * DIMV))[t];
  float4 m4 = ((const float4*)(msrc + (size_t)row * DIMV))[t];
  float sx = x4.x * x4.x + x4.y * x4.y + x4.z * x4.z + x4.w * x4.w;
  float sm = m4.x * m4.x + m4.y * m4.y + m4.z * m4.z + m4.w * m4.w;
  sx = blockReduceSum(sx, red);
  sm = blockReduceSum(sm, red);

  float xn = fmaxf(sqrtf(sx), 1e-15f);
  float mxn = fmaxf(sqrtf(sm), 1e-15f);
  float cx = fminf(xn, 1.0f - 1e-7f);
  float t1 = tanhf(mxn / xn * atanhf(cx));
  float s1 = t1 / mxn;

  float yn = fmaxf(fabsf(t1), 1e-15f);
  float a = atanhf(fminf(yn, 1.0f - 1e-7f)) / yn;
  float k1 = a * s1;
  float4 u = make_float4(fmaxf(k1 * m4.x, 0.0f), fmaxf(k1 * m4.y, 0.0f),
                         fmaxf(k1 * m4.z, 0.0f), fmaxf(k1 * m4.w, 0.0f));
  float su = u.x * u.x + u.y * u.y + u.z * u.z + u.w * u.w;
  su = blockReduceSum(su, red);

  float un = fmaxf(sqrtf(su), 1e-15f);
  float t2 = tanhf(un);
  float s2 = t2 / un;
  if (t2 > 0.996f) s2 *= 0.996f / t2;
  float4 o = make_float4(s2 * u.x, s2 * u.y, s2 * u.z, s2 * u.w);
  ((float4*)(dst + (size_t)row * DIMV))[t] = o;

  if (denom) {
    ((float4*)orow)[t] = o;
    __syncthreads();
    if (t < NHEADS) {
      float s = 0.0f;
#pragma unroll
      for (int i = 0; i < HEADD; ++i) {
        float v = orow[t * HEADD + i];
        s = fmaf(v, v, s);
      }
      denom[t * N_NODES + row] = fmaxf(1.0f - s, 1e-15f);
    }
  }
}

// ---------- v2: in-place K -> denominator*(elu(K/denom_pt)+1)*mask; accumulate v2_sum ----------
__global__ __launch_bounds__(256) void v2_kernel(float* __restrict__ kbuf,
                                                 const float* __restrict__ denom,
                                                 const float* __restrict__ mask,
                                                 float* __restrict__ v2sum) {
  const int t = threadIdx.x;
  const int c0 = t * 4;
  const int h = t >> 4;
  const int row0 = blockIdx.x * 64;
  float a0 = 0, a1 = 0, a2 = 0, a3 = 0;
  for (int r = 0; r < 64; ++r) {
    const int row = row0 + r;
    const float dp = denom[h * N_NODES + row];
    const float gamma = 2.0f / dp;
    const float den = clampabs(gamma - 1.0f, 1e-10f);
    const float mk = mask[row];
    const float invdp = 1.0f / dp;
    float4 kv = *(const float4*)(kbuf + (size_t)row * DIMV + c0);
    float4 v;
    v.x = den * elup1(kv.x * invdp) * mk;
    v.y = den * elup1(kv.y * invdp) * mk;
    v.z = den * elup1(kv.z * invdp) * mk;
    v.w = den * elup1(kv.w * invdp) * mk;
    *(float4*)(kbuf + (size_t)row * DIMV + c0) = v;
    a0 += v.x; a1 += v.y; a2 += v.z; a3 += v.w;
  }
  atomicAdd(&v2sum[c0 + 0], a0);
  atomicAdd(&v2sum[c0 + 1], a1);
  atomicAdd(&v2sum[c0 + 2], a2);
  atomicAdd(&v2sum[c0 + 3], a3);
}

// ---------- context[h][d][e] = sum_n v2[h,n,d] * (gamma/denominator * mask * V)[h,n,e] ----------
__global__ __launch_bounds__(256) void context_kernel(const float* __restrict__ v2buf,
                                                      const float* __restrict__ vbuf,
                                                      const float* __restrict__ denom,
                                                      const float* __restrict__ mask,
                                                      float* __restrict__ ctx) {
  __shared__ float s2[64][65];
  __shared__ float sx[64][65];
  const int h = blockIdx.y;
  const int t = threadIdx.x;
  const int d0 = (t >> 4) * 4;
  const int e0 = (t & 15) * 4;
  float acc[4][4];
#pragma unroll
  for (int i = 0; i < 4; ++i)
#pragma unroll
    for (int j = 0; j < 4; ++j) acc[i][j] = 0.0f;

  const int rbase = blockIdx.x * 1024;
  for (int c = 0; c < 16; ++c) {
#pragma unroll
    for (int i = 0; i < 4; ++i) {
      int f = i * 256 + t;
      int r = f >> 4;
      int cc = (f & 15) * 4;
      int row = rbase + c * 64 + r;
      float4 a = *(const float4*)(v2buf + (size_t)row * DIMV + h * HEADD + cc);
      s2[r][cc + 0] = a.x; s2[r][cc + 1] = a.y; s2[r][cc + 2] = a.z; s2[r][cc + 3] = a.w;
      float dp = denom[h * N_NODES + row];
      float gamma = 2.0f / dp;
      float den = clampabs(gamma - 1.0f, 1e-10f);
      float c1 = gamma / den * mask[row];
      float4 b = *(const float4*)(vbuf + (size_t)row * DIMV + h * HEADD + cc);
      sx[r][cc + 0] = c1 * b.x; sx[r][cc + 1] = c1 * b.y;
      sx[r][cc + 2] = c1 * b.z; sx[r][cc + 3] = c1 * b.w;
    }
    __syncthreads();
    for (int r = 0; r < 64; ++r) {
      float av[4], bv[4];
#pragma unroll
      for (int i = 0; i < 4; ++i) av[i] = s2[r][d0 + i];
#pragma unroll
      for (int j = 0; j < 4; ++j) bv[j] = sx[r][e0 + j];
#pragma unroll
      for (int i = 0; i < 4; ++i)
#pragma unroll
        for (int j = 0; j < 4; ++j) acc[i][j] = fmaf(av[i], bv[j], acc[i][j]);
    }
    __syncthreads();
  }
#pragma unroll
  for (int i = 0; i < 4; ++i)
#pragma unroll
    for (int j = 0; j < 4; ++j)
      atomicAdd(&ctx[h * 4096 + (d0 + i) * 64 + (e0 + j)], acc[i][j]);
}

// ---------- out: v1 = elu(Q/dp)+1; D = v1.v2sum; out = (v1@ctx)*Dinv; project; mobius*0.5; project ----------
__global__ __launch_bounds__(256) void out_kernel(float* __restrict__ qbuf,
                                                  const float* __restrict__ denom,
                                                  const float* __restrict__ v2sum,
                                                  const float* __restrict__ ctx) {
  __shared__ float sctx[64][65];
  __shared__ float sv2s[64];
  const int h = blockIdx.y;
  const int t = threadIdx.x;
#pragma unroll
  for (int i = 0; i < 4; ++i) {
    int f = i * 256 + t;
    int r = f >> 4;
    int cc = (f & 15) * 4;
    float4 v = *(const float4*)(ctx + h * 4096 + r * 64 + cc);
    sctx[r][cc + 0] = v.x; sctx[r][cc + 1] = v.y; sctx[r][cc + 2] = v.z; sctx[r][cc + 3] = v.w;
  }
  if (t < HEADD) sv2s[t] = v2sum[h * HEADD + t];
  __syncthreads();

  const int wave = t >> 6;
  const int lane = t & 63;
  for (int it = 0; it < 16; ++it) {
    const int n = blockIdx.x * 64 + it * 4 + wave;
    const float dp = denom[h * N_NODES + n];
    const float q = qbuf[(size_t)n * DIMV + h * HEADD + lane];
    const float v1 = elup1(q / dp);
    float D = waveReduceSum(v1 * sv2s[lane]);
    const float Dinv = 1.0f / (D == 0.0f ? 1e-5f : D);
    float o = 0.0f;
#pragma unroll
    for (int d = 0; d < 64; ++d) {
      float v1d = __shfl(v1, d);
      o = fmaf(v1d, sctx[d][lane], o);
    }
    o *= Dinv;
    float s = waveReduceSum(o * o);
    float n1 = fmaxf(sqrtf(s), 1e-15f);
    if (n1 > 0.996f) o *= 0.996f / n1;
    float xn = fmaxf(fminf(n1, 0.996f), 1e-15f);
    float cx = fminf(xn, 1.0f - 1e-7f);
    float t2 = tanhf(0.5f * atanhf(cx));
    o *= t2 / xn;
    if (t2 > 0.996f) o *= 0.996f / t2;
    qbuf[(size_t)n * DIMV + h * HEADD + lane] = o;
  }
}

// ---------- launch ----------

extern "C" void kernel_launch(void* const* d_in, const int* in_sizes, int n_in,
                              void* d_out, int out_size, void* d_ws, size_t ws_size,
                              hipStream_t stream) {
  const float* X = (const float*)d_in[0];
  const float* mask = (const float*)d_in[1];
  const float* Wq = (const float*)d_in[2];
  const float* bq = (const float*)d_in[3];
  const float* Wk = (const float*)d_in[4];
  const float* bk = (const float*)d_in[5];
  const float* Wv = (const float*)d_in[6];
  const float* Wff = (const float*)d_in[7];
  float* out = (float*)d_out;

  const size_t MAT = (size_t)N_NODES * DIMV;
  float* bufQ = (float*)d_ws;                       // Wk^T (temp) -> Q -> comb
  float* bufK = bufQ + MAT;                         // Wv^T (temp) -> K -> v2
  float* bufV = bufK + MAT;                         // X@Wv -> V; later Wq^T / Wff^T (temp)
  float* denom = bufV + MAT;                        // [16][16384]
  float* v2sum = denom + (size_t)NHEADS * N_NODES;  // [1024]
  float* ctx = v2sum + 1024;                        // [16][64][64]
  const size_t need = (3 * MAT + (size_t)NHEADS * N_NODES + 1024 + 4096 * NHEADS) * sizeof(float);
  if (ws_size < need) return;

  dim3 tgrid(32, 32);
  dim3 ggrid(DIMV / 128, N_NODES / 128);

  // V path: Wv^T staged in (dead) bufK
  transpose1024<<<tgrid, 256, 0, stream>>>(Wv, bufK);
  gemm_mfma<0, 0, false, false><<<ggrid, 256, 0, stream>>>(X, bufK, nullptr, bufV);
  rowtrans_kernel<<<N_NODES, 256, 0, stream>>>(X, bufV, bufV, denom);
  // K path: Wk^T staged in (dead) bufQ
  transpose1024<<<tgrid, 256, 0, stream>>>(Wk, bufQ);
  gemm_mfma<0, 0, false, true><<<ggrid, 256, 0, stream>>>(X, bufQ, bk, bufK);
  hipMemsetAsync(v2sum, 0, (1024 + 4096 * NHEADS) * sizeof(float), stream);
  v2_kernel<<<N_NODES / 64, 256, 0, stream>>>(bufK, denom, mask, v2sum);
  // context
  context_kernel<<<dim3(16, NHEADS), 256, 0, stream>>>(bufK, bufV, denom, mask, ctx);
  // Q path: Wq^T staged in bufV (V is dead after context)
  transpose1024<<<tgrid, 256, 0, stream>>>(Wq, bufV);
  gemm_mfma<0, 0, false, true><<<ggrid, 256, 0, stream>>>(X, bufV, bq, bufQ);
  out_kernel<<<dim3(N_NODES / 64, NHEADS), 256, 0, stream>>>(bufQ, denom, v2sum, ctx);
  // final: 3-pass split bf16 GEMM comb@Wff -> out, then rowtrans
  transpose1024<<<tgrid, 256, 0, stream>>>(Wff, bufV);
  gemm_mfma<0, 0, false, false><<<ggrid, 256, 0, stream>>>(bufQ, bufV, nullptr, out);  // hi*hi
  gemm_mfma<1, 0, true, false><<<ggrid, 256, 0, stream>>>(bufQ, bufV, nullptr, out);   // lo*hi
  gemm_mfma<0, 1, true, false><<<ggrid, 256, 0, stream>>>(bufQ, bufV, nullptr, out);   // hi*lo
  rowtrans_kernel<<<N_NODES, 256, 0, stream>>>(bufQ, out, out, nullptr);
}

// Round 3
// 687.370 us; speedup vs baseline: 2.8992x; 1.5434x over previous
//
#include <hip/hip_runtime.h>
#include <hip/hip_bf16.h>
#include <math.h>

#define N_NODES 16384
#define DIMV 1024
#define NHEADS 16
#define HEADD 64

typedef __attribute__((ext_vector_type(8))) short short8;
typedef __attribute__((ext_vector_type(4))) float f32x4;
typedef unsigned short ushort_t;

// async global->LDS, 16B per lane; LDS dest is wave-uniform base + lane*16
#define GLD16(gptr, lptr)                                                                 \
  __builtin_amdgcn_global_load_lds((const __attribute__((address_space(1))) void*)(gptr), \
                                   (__attribute__((address_space(3))) void*)(lptr), 16, 0, 0)

// ---------- helpers ----------

__device__ __forceinline__ float waveReduceSum(float v) {
#pragma unroll
  for (int m = 32; m; m >>= 1) v += __shfl_xor(v, m);
  return v;
}

__device__ __forceinline__ float blockReduceSum(float v, float* red) {
  float w = waveReduceSum(v);
  __syncthreads();
  if ((threadIdx.x & 63) == 0) red[threadIdx.x >> 6] = w;
  __syncthreads();
  return red[0] + red[1] + red[2] + red[3];
}

__device__ __forceinline__ float elup1(float z) {
  return z > 0.0f ? z + 1.0f : expm1f(z) + 1.0f;
}

__device__ __forceinline__ float clampabs(float x, float eps) {
  float s = (x >= 0.0f) ? 1.0f : -1.0f;
  return s * fmaxf(fabsf(x), eps);
}

// fp32 -> bf16 bits, RNE
__device__ __forceinline__ ushort_t f2b(float x) {
  unsigned u = __float_as_uint(x);
  unsigned r = (u + 0x7FFFu + ((u >> 16) & 1u)) >> 16;
  return (ushort_t)r;
}
__device__ __forceinline__ float b2f(ushort_t h) {
  return __uint_as_float(((unsigned)h) << 16);
}

// ---------- X -> bf16 conversion (one shot) ----------
__global__ __launch_bounds__(256) void cvt_bf16_kernel(const float* __restrict__ src,
                                                       ushort_t* __restrict__ dst) {
  size_t i = ((size_t)blockIdx.x * 256 + threadIdx.x) * 8;
  float4 a = *(const float4*)(src + i);
  float4 b = *(const float4*)(src + i + 4);
  ushort_t h[8] = {f2b(a.x), f2b(a.y), f2b(a.z), f2b(a.w),
                   f2b(b.x), f2b(b.y), f2b(b.z), f2b(b.w)};
  *(uint4*)(dst + i) = *(uint4*)h;
}

// ---------- weight transpose -> bf16 (hi, and optional lo residual) ----------
template <bool LO>
__global__ __launch_bounds__(256) void transW_kernel(const float* __restrict__ src,
                                                     ushort_t* __restrict__ hi,
                                                     ushort_t* __restrict__ lo) {
  __shared__ float tile[32][33];
  const int bx = blockIdx.x * 32, by = blockIdx.y * 32;
  const int tx = threadIdx.x & 31, ty = threadIdx.x >> 5;
#pragma unroll
  for (int i = 0; i < 32; i += 8) tile[ty + i][tx] = src[(size_t)(by + ty + i) * DIMV + bx + tx];
  __syncthreads();
#pragma unroll
  for (int i = 0; i < 32; i += 8) {
    float v = tile[tx][ty + i];
    ushort_t h = f2b(v);
    hi[(size_t)(bx + ty + i) * DIMV + by + tx] = h;
    if (LO) lo[(size_t)(bx + ty + i) * DIMV + by + tx] = f2b(v - b2f(h));
  }
}

// ---------- bf16 MFMA GEMM (m97 structure): C[Mx1024] (+)= A @ Bt^T (+bias) ----------
// A: [M][1024] bf16, Bt: [1024][1024] bf16 (n-major, k-contiguous). Both staged via
// global_load_lds width=16 into linear LDS [128][32]. 128x128 tile, BK=32, 4 waves 2x2.
template <bool ACCUM, bool BIAS>
__global__ __launch_bounds__(256) void gemm_bf(const ushort_t* __restrict__ A,
                                               const ushort_t* __restrict__ Bt,
                                               const float* __restrict__ bias,
                                               float* __restrict__ C) {
  __shared__ ushort_t As[128][32];
  __shared__ ushort_t Bs[128][32];
  const int t = threadIdx.x;
  const int bm = blockIdx.y * 128;
  const int bn = blockIdx.x * 128;
  const int w = t >> 6, lane = t & 63, l15 = lane & 15;
  const int wr = (w >> 1) * 64, wc = (w & 1) * 64;
  const int kk = (lane >> 4) * 8;

  // two 1KB chunks per wave per operand: chunk c covers lane-linear idx c*64+lane,
  // LDS byte = idx*16 = row*64 + kc*2  (row = idx>>2, kc = (idx&3)*8)
  const int c0 = w, c1 = 4 + w;
  const int x0 = c0 * 64 + lane, x1 = c1 * 64 + lane;
  const ushort_t* gA0 = A + (size_t)(bm + (x0 >> 2)) * DIMV + (x0 & 3) * 8;
  const ushort_t* gA1 = A + (size_t)(bm + (x1 >> 2)) * DIMV + (x1 & 3) * 8;
  const ushort_t* gB0 = Bt + (size_t)(bn + (x0 >> 2)) * DIMV + (x0 & 3) * 8;
  const ushort_t* gB1 = Bt + (size_t)(bn + (x1 >> 2)) * DIMV + (x1 & 3) * 8;
  ushort_t* lA0 = &As[0][0] + c0 * 512;
  ushort_t* lA1 = &As[0][0] + c1 * 512;
  ushort_t* lB0 = &Bs[0][0] + c0 * 512;
  ushort_t* lB1 = &Bs[0][0] + c1 * 512;

  f32x4 acc[4][4];
#pragma unroll
  for (int i = 0; i < 4; ++i)
#pragma unroll
    for (int j = 0; j < 4; ++j) acc[i][j] = (f32x4){0.f, 0.f, 0.f, 0.f};

  for (int k0 = 0; k0 < DIMV; k0 += 32) {
    GLD16(gA0 + k0, lA0);
    GLD16(gA1 + k0, lA1);
    GLD16(gB0 + k0, lB0);
    GLD16(gB1 + k0, lB1);
    __syncthreads();
    short8 af[4], bf[4];
#pragma unroll
    for (int i = 0; i < 4; ++i) af[i] = *(const short8*)&As[wr + i * 16 + l15][kk];
#pragma unroll
    for (int j = 0; j < 4; ++j) bf[j] = *(const short8*)&Bs[wc + j * 16 + l15][kk];
#pragma unroll
    for (int i = 0; i < 4; ++i)
#pragma unroll
      for (int j = 0; j < 4; ++j)
        acc[i][j] = __builtin_amdgcn_mfma_f32_16x16x32_bf16(af[i], bf[j], acc[i][j], 0, 0, 0);
    __syncthreads();
  }

  // C/D layout: col = lane&15, row = (lane>>4)*4 + r
  const int rbase = (lane >> 4) * 4;
#pragma unroll
  for (int j = 0; j < 4; ++j) {
    const int col = bn + wc + j * 16 + l15;
    float bb = BIAS ? bias[col] : 0.0f;
#pragma unroll
    for (int i = 0; i < 4; ++i) {
#pragma unroll
      for (int r = 0; r < 4; ++r) {
        const int row = bm + wr + i * 16 + rbase + r;
        float v = acc[i][j][r] + bb;
        if (ACCUM)
          C[(size_t)row * DIMV + col] += v;
        else
          C[(size_t)row * DIMV + col] = v;
      }
    }
  }
}

// ---------- row transform: mobius_matvec tail + kappa_relu; optional bf16 dst, per-head denom ----------
template <bool BFDST>
__global__ __launch_bounds__(256) void rowtrans_kernel(const float* __restrict__ xsrc,
                                                       const float* __restrict__ msrc,
                                                       void* __restrict__ dstv,
                                                       float* __restrict__ denom) {
  __shared__ float red[4];
  __shared__ float orow[DIMV];
  const int row = blockIdx.x;
  const int t = threadIdx.x;
  float4 x4 = ((const float4*)(xsrc + (size_t)row * DIMV))[t];
  float4 m4 = ((const float4*)(msrc + (size_t)row * DIMV))[t];
  float sx = x4.x * x4.x + x4.y * x4.y + x4.z * x4.z + x4.w * x4.w;
  float sm = m4.x * m4.x + m4.y * m4.y + m4.z * m4.z + m4.w * m4.w;
  sx = blockReduceSum(sx, red);
  sm = blockReduceSum(sm, red);

  float xn = fmaxf(sqrtf(sx), 1e-15f);
  float mxn = fmaxf(sqrtf(sm), 1e-15f);
  float cx = fminf(xn, 1.0f - 1e-7f);
  float t1 = tanhf(mxn / xn * atanhf(cx));
  float s1 = t1 / mxn;

  float yn = fmaxf(fabsf(t1), 1e-15f);
  float a = atanhf(fminf(yn, 1.0f - 1e-7f)) / yn;
  float k1 = a * s1;
  float4 u = make_float4(fmaxf(k1 * m4.x, 0.0f), fmaxf(k1 * m4.y, 0.0f),
                         fmaxf(k1 * m4.z, 0.0f), fmaxf(k1 * m4.w, 0.0f));
  float su = u.x * u.x + u.y * u.y + u.z * u.z + u.w * u.w;
  su = blockReduceSum(su, red);

  float un = fmaxf(sqrtf(su), 1e-15f);
  float t2 = tanhf(un);
  float s2 = t2 / un;
  if (t2 > 0.996f) s2 *= 0.996f / t2;
  float4 o = make_float4(s2 * u.x, s2 * u.y, s2 * u.z, s2 * u.w);
  if (BFDST) {
    ushort_t h[4] = {f2b(o.x), f2b(o.y), f2b(o.z), f2b(o.w)};
    ((uint2*)((ushort_t*)dstv + (size_t)row * DIMV))[t] = *(uint2*)h;
  } else {
    ((float4*)((float*)dstv + (size_t)row * DIMV))[t] = o;
  }

  if (denom) {
    ((float4*)orow)[t] = o;
    __syncthreads();
    if (t < NHEADS) {
      float s = 0.0f;
#pragma unroll
      for (int i = 0; i < HEADD; ++i) {
        float v = orow[t * HEADD + i];
        s = fmaf(v, v, s);
      }
      denom[t * N_NODES + row] = fmaxf(1.0f - s, 1e-15f);
    }
  }
}

// ---------- v2: in-place K -> denominator*(elu(K/denom_pt)+1)*mask; accumulate v2_sum ----------
__global__ __launch_bounds__(256) void v2_kernel(float* __restrict__ kbuf,
                                                 const float* __restrict__ denom,
                                                 const float* __restrict__ mask,
                                                 float* __restrict__ v2sum) {
  const int t = threadIdx.x;
  const int c0 = t * 4;
  const int h = t >> 4;
  const int row0 = blockIdx.x * 64;
  float a0 = 0, a1 = 0, a2 = 0, a3 = 0;
  for (int r = 0; r < 64; ++r) {
    const int row = row0 + r;
    const float dp = denom[h * N_NODES + row];
    const float gamma = 2.0f / dp;
    const float den = clampabs(gamma - 1.0f, 1e-10f);
    const float mk = mask[row];
    const float invdp = 1.0f / dp;
    float4 kv = *(const float4*)(kbuf + (size_t)row * DIMV + c0);
    float4 v;
    v.x = den * elup1(kv.x * invdp) * mk;
    v.y = den * elup1(kv.y * invdp) * mk;
    v.z = den * elup1(kv.z * invdp) * mk;
    v.w = den * elup1(kv.w * invdp) * mk;
    *(float4*)(kbuf + (size_t)row * DIMV + c0) = v;
    a0 += v.x; a1 += v.y; a2 += v.z; a3 += v.w;
  }
  atomicAdd(&v2sum[c0 + 0], a0);
  atomicAdd(&v2sum[c0 + 1], a1);
  atomicAdd(&v2sum[c0 + 2], a2);
  atomicAdd(&v2sum[c0 + 3], a3);
}

// ---------- ctxT[h][e][d] = sum_n v2[h,n,d] * (gamma/denominator * mask * V)[h,n,e] ----------
// V is bf16. Output TRANSPOSED (e-major) for the out-kernel's B staging.
__global__ __launch_bounds__(256) void context_kernel(const float* __restrict__ v2buf,
                                                      const ushort_t* __restrict__ vbuf,
                                                      const float* __restrict__ denom,
                                                      const float* __restrict__ mask,
                                                      float* __restrict__ ctxT) {
  __shared__ float s2[64][65];
  __shared__ float sx[64][65];
  const int h = blockIdx.y;
  const int t = threadIdx.x;
  const int d0 = (t >> 4) * 4;
  const int e0 = (t & 15) * 4;
  float acc[4][4];
#pragma unroll
  for (int i = 0; i < 4; ++i)
#pragma unroll
    for (int j = 0; j < 4; ++j) acc[i][j] = 0.0f;

  const int rbase = blockIdx.x * 1024;
  for (int c = 0; c < 16; ++c) {
#pragma unroll
    for (int i = 0; i < 4; ++i) {
      int f = i * 256 + t;
      int r = f >> 4;
      int cc = (f & 15) * 4;
      int row = rbase + c * 64 + r;
      float4 a = *(const float4*)(v2buf + (size_t)row * DIMV + h * HEADD + cc);
      s2[r][cc + 0] = a.x; s2[r][cc + 1] = a.y; s2[r][cc + 2] = a.z; s2[r][cc + 3] = a.w;
      float dp = denom[h * N_NODES + row];
      float gamma = 2.0f / dp;
      float den = clampabs(gamma - 1.0f, 1e-10f);
      float c1 = gamma / den * mask[row];
      uint2 braw = *(const uint2*)(vbuf + (size_t)row * DIMV + h * HEADD + cc);
      ushort_t* bh = (ushort_t*)&braw;
      sx[r][cc + 0] = c1 * b2f(bh[0]); sx[r][cc + 1] = c1 * b2f(bh[1]);
      sx[r][cc + 2] = c1 * b2f(bh[2]); sx[r][cc + 3] = c1 * b2f(bh[3]);
    }
    __syncthreads();
    for (int r = 0; r < 64; ++r) {
      float av[4], bv[4];
#pragma unroll
      for (int i = 0; i < 4; ++i) av[i] = s2[r][d0 + i];
#pragma unroll
      for (int j = 0; j < 4; ++j) bv[j] = sx[r][e0 + j];
#pragma unroll
      for (int i = 0; i < 4; ++i)
#pragma unroll
        for (int j = 0; j < 4; ++j) acc[i][j] = fmaf(av[i], bv[j], acc[i][j]);
    }
    __syncthreads();
  }
#pragma unroll
  for (int i = 0; i < 4; ++i)
#pragma unroll
    for (int j = 0; j < 4; ++j)
      atomicAdd(&ctxT[h * 4096 + (e0 + j) * 64 + (d0 + i)], acc[i][j]);
}

// ---------- out (MFMA): v1 = elu(Q/dp)+1; [out|D] = v1 @ [ctx|v2sum]; tail; emit comb fp32+hi/lo ----------
// Block: 256 rows x one head. A = v1 [256][64] bf16 LDS; B = [80 cols][64] bf16 LDS
// (cols 0..63 = ctx[d][e] via ctxT, col 64 = v2sum, 65..79 = 0). 4 waves x 64 rows each.
__global__ __launch_bounds__(256) void out_mfma_kernel(float* __restrict__ qbuf,
                                                       const float* __restrict__ denom,
                                                       const float* __restrict__ v2sum,
                                                       const float* __restrict__ ctxT,
                                                       ushort_t* __restrict__ combHi,
                                                       ushort_t* __restrict__ combLo) {
  __shared__ ushort_t v1lds[256][88];  // 176B row stride: 16B-aligned, 2-way banks
  __shared__ ushort_t Blds[80][88];
  const int h = blockIdx.y;
  const int bm = blockIdx.x * 256;
  const int t = threadIdx.x;
  const int w = t >> 6, lane = t & 63, l15 = lane & 15;
  const int kk = (lane >> 4) * 8;

  for (int idx = t; idx < 80 * 64; idx += 256) {
    int e = idx >> 6, d = idx & 63;
    float v = 0.0f;
    if (e < 64) v = ctxT[h * 4096 + e * 64 + d];
    else if (e == 64) v = v2sum[h * 64 + d];
    Blds[e][d] = f2b(v);
  }
  const int srow = t >> 4, sq = (t & 15) * 4;
#pragma unroll
  for (int it = 0; it < 16; ++it) {
    int row = it * 16 + srow;
    float inv = 1.0f / denom[h * N_NODES + bm + row];
    float4 q = *(const float4*)(qbuf + (size_t)(bm + row) * DIMV + h * HEADD + sq);
    ushort_t hh[4] = {f2b(elup1(q.x * inv)), f2b(elup1(q.y * inv)),
                      f2b(elup1(q.z * inv)), f2b(elup1(q.w * inv))};
    *(uint2*)&v1lds[row][sq] = *(uint2*)hh;
  }
  __syncthreads();

  f32x4 acc[4][5];
#pragma unroll
  for (int i = 0; i < 4; ++i)
#pragma unroll
    for (int j = 0; j < 5; ++j) acc[i][j] = (f32x4){0.f, 0.f, 0.f, 0.f};
#pragma unroll
  for (int ks = 0; ks < 64; ks += 32) {
    short8 af[4], bfr[5];
#pragma unroll
    for (int i = 0; i < 4; ++i) af[i] = *(const short8*)&v1lds[w * 64 + i * 16 + l15][ks + kk];
#pragma unroll
    for (int j = 0; j < 5; ++j) bfr[j] = *(const short8*)&Blds[j * 16 + l15][ks + kk];
#pragma unroll
    for (int i = 0; i < 4; ++i)
#pragma unroll
      for (int j = 0; j < 5; ++j)
        acc[i][j] = __builtin_amdgcn_mfma_f32_16x16x32_bf16(af[i], bfr[j], acc[i][j], 0, 0, 0);
  }

  const int g4 = (lane >> 4) * 4;
#pragma unroll
  for (int i = 0; i < 4; ++i) {
#pragma unroll
    for (int r = 0; r < 4; ++r) {
      const int row = bm + w * 64 + i * 16 + g4 + r;
      float D = __shfl(acc[i][4][r], lane & 48);  // col 64 lives at l15==0 of each group
      float Dinv = 1.0f / (D == 0.0f ? 1e-5f : D);
      float o[4];
      float s = 0.0f;
#pragma unroll
      for (int j = 0; j < 4; ++j) {
        o[j] = acc[i][j][r] * Dinv;
        s = fmaf(o[j], o[j], s);
      }
      s += __shfl_xor(s, 1); s += __shfl_xor(s, 2);
      s += __shfl_xor(s, 4); s += __shfl_xor(s, 8);
      float n1 = fmaxf(sqrtf(s), 1e-15f);
      float sc = 1.0f;
      if (n1 > 0.996f) sc = 0.996f / n1;           // project
      float xn = fmaxf(fminf(n1, 0.996f), 1e-15f);
      float cx = fminf(xn, 1.0f - 1e-7f);
      float t2 = tanhf(0.5f * atanhf(cx));         // mobius_scalar_mul(0.5)
      sc *= t2 / xn;
      if (t2 > 0.996f) sc *= 0.996f / t2;          // project
#pragma unroll
      for (int j = 0; j < 4; ++j) {
        float ov = o[j] * sc;
        size_t off = (size_t)row * DIMV + h * HEADD + j * 16 + l15;
        qbuf[off] = ov;
        ushort_t hi = f2b(ov);
        combHi[off] = hi;
        combLo[off] = f2b(ov - b2f(hi));
      }
    }
  }
}

// ---------- launch ----------

extern "C" void kernel_launch(void* const* d_in, const int* in_sizes, int n_in,
                              void* d_out, int out_size, void* d_ws, size_t ws_size,
                              hipStream_t stream) {
  const float* X = (const float*)d_in[0];
  const float* mask = (const float*)d_in[1];
  const float* Wq = (const float*)d_in[2];
  const float* bq = (const float*)d_in[3];
  const float* Wk = (const float*)d_in[4];
  const float* bk = (const float*)d_in[5];
  const float* Wv = (const float*)d_in[6];
  const float* Wff = (const float*)d_in[7];
  float* out = (float*)d_out;

  const size_t MAT = (size_t)N_NODES * DIMV;
  char* p = (char*)d_ws;
  float* bufQ = (float*)p;            p += MAT * 4;   // mxV temp -> Q -> comb (fp32)
  float* bufK = (float*)p;            p += MAT * 4;   // K -> v2; later combHi/combLo (bf16)
  ushort_t* Vbf = (ushort_t*)p;       p += MAT * 2;   // V bf16; later WffHi/WffLo
  ushort_t* Xbf = (ushort_t*)p;       p += MAT * 2;   // X bf16
  float* denom = (float*)p;           p += (size_t)NHEADS * N_NODES * 4;
  float* v2sum = (float*)p;           p += 1024 * 4;
  float* ctxT = (float*)p;            p += (size_t)NHEADS * 4096 * 4;
  const size_t need = (size_t)(p - (char*)d_ws);
  if (ws_size < need) return;

  ushort_t* Wt = (ushort_t*)d_out;          // 2MB scratch inside d_out (free until final passes)
  ushort_t* WffHi = Vbf;                    // Vbf dead after context
  ushort_t* WffLo = Vbf + (size_t)DIMV * DIMV;
  ushort_t* combHi = (ushort_t*)bufK;       // bufK dead after context
  ushort_t* combLo = combHi + MAT;

  dim3 tgrid(32, 32);
  dim3 ggrid(DIMV / 128, N_NODES / 128);

  cvt_bf16_kernel<<<MAT / 2048, 256, 0, stream>>>(X, Xbf);
  // V path
  transW_kernel<false><<<tgrid, 256, 0, stream>>>(Wv, Wt, nullptr);
  gemm_bf<false, false><<<ggrid, 256, 0, stream>>>(Xbf, Wt, nullptr, bufQ);
  rowtrans_kernel<true><<<N_NODES, 256, 0, stream>>>(X, bufQ, Vbf, denom);
  // K path -> v2, v2_sum
  transW_kernel<false><<<tgrid, 256, 0, stream>>>(Wk, Wt, nullptr);
  gemm_bf<false, true><<<ggrid, 256, 0, stream>>>(Xbf, Wt, bk, bufK);
  hipMemsetAsync(v2sum, 0, (1024 + 4096 * NHEADS) * sizeof(float), stream);
  v2_kernel<<<N_NODES / 64, 256, 0, stream>>>(bufK, denom, mask, v2sum);
  // context (transposed output)
  context_kernel<<<dim3(16, NHEADS), 256, 0, stream>>>(bufK, Vbf, denom, mask, ctxT);
  // Q path -> attention out (in-place comb + bf16 hi/lo)
  transW_kernel<false><<<tgrid, 256, 0, stream>>>(Wq, Wt, nullptr);
  gemm_bf<false, true><<<ggrid, 256, 0, stream>>>(Xbf, Wt, bq, bufQ);
  out_mfma_kernel<<<dim3(N_NODES / 256, NHEADS), 256, 0, stream>>>(bufQ, denom, v2sum, ctxT,
                                                                   combHi, combLo);
  // final: 3-pass split bf16 GEMM comb@Wff -> out, then rowtrans
  transW_kernel<true><<<tgrid, 256, 0, stream>>>(Wff, WffHi, WffLo);
  gemm_bf<false, false><<<ggrid, 256, 0, stream>>>(combHi, WffHi, nullptr, out);
  gemm_bf<true, false><<<ggrid, 256, 0, stream>>>(combLo, WffHi, nullptr, out);
  gemm_bf<true, false><<<ggrid, 256, 0, stream>>>(combHi, WffLo, nullptr, out);
  rowtrans_kernel<false><<<N_NODES, 256, 0, stream>>>(bufQ, out, out, nullptr);
}

// Round 4
// 605.275 us; speedup vs baseline: 3.2925x; 1.1356x over previous
//
#include <hip/hip_runtime.h>
#include <hip/hip_bf16.h>
#include <math.h>

#define N_NODES 16384
#define DIMV 1024
#define NHEADS 16
#define HEADD 64

typedef __attribute__((ext_vector_type(8))) short short8;
typedef __attribute__((ext_vector_type(4))) float f32x4;
typedef unsigned short ushort_t;

// async global->LDS, 16B per lane; LDS dest is wave-uniform base + lane*16
#define GLD16(gptr, lptr)                                                                 \
  __builtin_amdgcn_global_load_lds((const __attribute__((address_space(1))) void*)(gptr), \
                                   (__attribute__((address_space(3))) void*)(lptr), 16, 0, 0)

// ---------- helpers ----------

__device__ __forceinline__ float waveReduceSum(float v) {
#pragma unroll
  for (int m = 32; m; m >>= 1) v += __shfl_xor(v, m);
  return v;
}

__device__ __forceinline__ float blockReduceSum(float v, float* red) {
  float w = waveReduceSum(v);
  __syncthreads();
  if ((threadIdx.x & 63) == 0) red[threadIdx.x >> 6] = w;
  __syncthreads();
  return red[0] + red[1] + red[2] + red[3];
}

__device__ __forceinline__ float elup1(float z) {
  return z > 0.0f ? z + 1.0f : expm1f(z) + 1.0f;
}

__device__ __forceinline__ float clampabs(float x, float eps) {
  float s = (x >= 0.0f) ? 1.0f : -1.0f;
  return s * fmaxf(fabsf(x), eps);
}

// fp32 -> bf16 bits, RNE
__device__ __forceinline__ ushort_t f2b(float x) {
  unsigned u = __float_as_uint(x);
  unsigned r = (u + 0x7FFFu + ((u >> 16) & 1u)) >> 16;
  return (ushort_t)r;
}
__device__ __forceinline__ float b2f(ushort_t h) {
  return __uint_as_float(((unsigned)h) << 16);
}

// ---------- X -> bf16 + row sumsq (one block per row) ----------
__global__ __launch_bounds__(256) void cvt_norm_kernel(const float* __restrict__ src,
                                                       ushort_t* __restrict__ dst,
                                                       float* __restrict__ rowsq) {
  __shared__ float red[4];
  const int row = blockIdx.x;
  const int t = threadIdx.x;
  float4 x4 = ((const float4*)(src + (size_t)row * DIMV))[t];
  ushort_t h[4] = {f2b(x4.x), f2b(x4.y), f2b(x4.z), f2b(x4.w)};
  ((uint2*)(dst + (size_t)row * DIMV))[t] = *(uint2*)h;
  float s = x4.x * x4.x + x4.y * x4.y + x4.z * x4.z + x4.w * x4.w;
  s = blockReduceSum(s, red);
  if (t == 0) rowsq[row] = s;
}

// ---------- weight transpose -> bf16 (hi, and optional lo residual) ----------
template <bool LO>
__global__ __launch_bounds__(256) void transW_kernel(const float* __restrict__ src,
                                                     ushort_t* __restrict__ hi,
                                                     ushort_t* __restrict__ lo) {
  __shared__ float tile[32][33];
  const int bx = blockIdx.x * 32, by = blockIdx.y * 32;
  const int tx = threadIdx.x & 31, ty = threadIdx.x >> 5;
#pragma unroll
  for (int i = 0; i < 32; i += 8) tile[ty + i][tx] = src[(size_t)(by + ty + i) * DIMV + bx + tx];
  __syncthreads();
#pragma unroll
  for (int i = 0; i < 32; i += 8) {
    float v = tile[tx][ty + i];
    ushort_t h = f2b(v);
    hi[(size_t)(bx + ty + i) * DIMV + by + tx] = h;
    if (LO) lo[(size_t)(bx + ty + i) * DIMV + by + tx] = f2b(v - b2f(h));
  }
}

// ---------- bf16 MFMA GEMM, BK=64 (m97 geometry), fused epilogues ----------
// A: [M][1024] bf16, Bt: [1024 n][1024 k] bf16. 128x128 tile, 4 waves 2x2, 4x4 frags.
// EPI 0: C = bf16(acc)            (V path, no bias)
// EPI 1: C = bf16(v1) = bf16(elup1((acc+b)/dp))                       (Q path)
// EPI 2: C = bf16(v2) = bf16(den*elup1((acc+b)/dp)*mask); v2sum +=    (K path)
template <int EPI>
__global__ __launch_bounds__(256) void gemm_bf(const ushort_t* __restrict__ A,
                                               const ushort_t* __restrict__ Bt,
                                               const float* __restrict__ bias,
                                               const float* __restrict__ denom,
                                               const float* __restrict__ mask,
                                               float* __restrict__ v2sum,
                                               ushort_t* __restrict__ C) {
  __shared__ ushort_t As[128][64];
  __shared__ ushort_t Bs[128][64];
  const int t = threadIdx.x;
  const int bm = blockIdx.y * 128;
  const int bn = blockIdx.x * 128;
  const int w = t >> 6, lane = t & 63, l15 = lane & 15;
  const int wr = (w >> 1) * 64, wc = (w & 1) * 64;
  const int kk = (lane >> 4) * 8;

  // staging: 16 chunks of 1KB per operand; wave w takes chunks w+4c. 1KB = 8 rows x 128B.
  const int scol = (lane & 7) * 8;
  const int r8 = lane >> 3;
  const ushort_t *gA[4], *gB[4];
  ushort_t *lA[4], *lB[4];
#pragma unroll
  for (int c = 0; c < 4; ++c) {
    const int chunk = w + 4 * c;
    const int row = chunk * 8 + r8;
    lA[c] = &As[0][0] + chunk * 512;
    lB[c] = &Bs[0][0] + chunk * 512;
    gA[c] = A + (size_t)(bm + row) * DIMV + scol;
    gB[c] = Bt + (size_t)(bn + row) * DIMV + scol;
  }

  f32x4 acc[4][4];
#pragma unroll
  for (int i = 0; i < 4; ++i)
#pragma unroll
    for (int j = 0; j < 4; ++j) acc[i][j] = (f32x4){0.f, 0.f, 0.f, 0.f};

  for (int k0 = 0; k0 < DIMV; k0 += 64) {
#pragma unroll
    for (int c = 0; c < 4; ++c) GLD16(gA[c] + k0, lA[c]);
#pragma unroll
    for (int c = 0; c < 4; ++c) GLD16(gB[c] + k0, lB[c]);
    __syncthreads();
#pragma unroll
    for (int ks = 0; ks < 2; ++ks) {
      short8 af[4], bf[4];
#pragma unroll
      for (int i = 0; i < 4; ++i) af[i] = *(const short8*)&As[wr + i * 16 + l15][ks * 32 + kk];
#pragma unroll
      for (int j = 0; j < 4; ++j) bf[j] = *(const short8*)&Bs[wc + j * 16 + l15][ks * 32 + kk];
#pragma unroll
      for (int i = 0; i < 4; ++i)
#pragma unroll
        for (int j = 0; j < 4; ++j)
          acc[i][j] = __builtin_amdgcn_mfma_f32_16x16x32_bf16(af[i], bf[j], acc[i][j], 0, 0, 0);
    }
    __syncthreads();
  }

  // epilogue. h is wave-uniform: cols span [bn+wc, bn+wc+64).
  const int rbase = (lane >> 4) * 4;
  const int h = (bn + wc) >> 6;
  float bb[4];
#pragma unroll
  for (int j = 0; j < 4; ++j) bb[j] = (EPI != 0) ? bias[bn + wc + j * 16 + l15] : 0.0f;
  float csum[4] = {0.f, 0.f, 0.f, 0.f};
#pragma unroll
  for (int i = 0; i < 4; ++i) {
#pragma unroll
    for (int r = 0; r < 4; ++r) {
      const int row = bm + wr + i * 16 + rbase + r;
      float invdp = 1.0f, den = 0.0f, mk = 0.0f;
      if (EPI != 0) invdp = 1.0f / denom[(size_t)h * N_NODES + row];
      if (EPI == 2) {
        den = clampabs(2.0f * invdp - 1.0f, 1e-10f);
        mk = mask[row];
      }
#pragma unroll
      for (int j = 0; j < 4; ++j) {
        const int col = bn + wc + j * 16 + l15;
        float val = acc[i][j][r] + bb[j];
        if (EPI == 1) val = elup1(val * invdp);
        if (EPI == 2) {
          val = den * elup1(val * invdp) * mk;
          csum[j] += val;
        }
        C[(size_t)row * DIMV + col] = f2b(val);
      }
    }
  }
  if (EPI == 2) {
#pragma unroll
    for (int j = 0; j < 4; ++j) atomicAdd(&v2sum[bn + wc + j * 16 + l15], csum[j]);
  }
}

// ---------- fused 3-term split GEMM: C = bf16(AhiBhi + AloBhi + AhiBlo), BK=32 ----------
__global__ __launch_bounds__(256) void gemm_split3(const ushort_t* __restrict__ Ahi,
                                                   const ushort_t* __restrict__ Alo,
                                                   const ushort_t* __restrict__ Bhi,
                                                   const ushort_t* __restrict__ Blo,
                                                   ushort_t* __restrict__ C) {
  __shared__ ushort_t AsH[128][32], AsL[128][32], BsH[128][32], BsL[128][32];
  const int t = threadIdx.x;
  const int bm = blockIdx.y * 128;
  const int bn = blockIdx.x * 128;
  const int w = t >> 6, lane = t & 63, l15 = lane & 15;
  const int wr = (w >> 1) * 64, wc = (w & 1) * 64;
  const int kk = (lane >> 4) * 8;

  // 8 chunks of 1KB per tile; wave w takes chunks w+4c, c in {0,1}. 1KB = 16 rows x 64B.
  const int scol = (lane & 3) * 8;
  const int r4 = lane >> 2;
  const ushort_t *gAH[2], *gAL[2], *gBH[2], *gBL[2];
  ushort_t *lAH[2], *lAL[2], *lBH[2], *lBL[2];
#pragma unroll
  for (int c = 0; c < 2; ++c) {
    const int chunk = w + 4 * c;
    const int row = chunk * 16 + r4;
    lAH[c] = &AsH[0][0] + chunk * 512;
    lAL[c] = &AsL[0][0] + chunk * 512;
    lBH[c] = &BsH[0][0] + chunk * 512;
    lBL[c] = &BsL[0][0] + chunk * 512;
    gAH[c] = Ahi + (size_t)(bm + row) * DIMV + scol;
    gAL[c] = Alo + (size_t)(bm + row) * DIMV + scol;
    gBH[c] = Bhi + (size_t)(bn + row) * DIMV + scol;
    gBL[c] = Blo + (size_t)(bn + row) * DIMV + scol;
  }

  f32x4 acc[4][4];
#pragma unroll
  for (int i = 0; i < 4; ++i)
#pragma unroll
    for (int j = 0; j < 4; ++j) acc[i][j] = (f32x4){0.f, 0.f, 0.f, 0.f};

  for (int k0 = 0; k0 < DIMV; k0 += 32) {
#pragma unroll
    for (int c = 0; c < 2; ++c) {
      GLD16(gAH[c] + k0, lAH[c]);
      GLD16(gAL[c] + k0, lAL[c]);
      GLD16(gBH[c] + k0, lBH[c]);
      GLD16(gBL[c] + k0, lBL[c]);
    }
    __syncthreads();
    short8 afH[4], afL[4], bfH[4], bfL[4];
#pragma unroll
    for (int i = 0; i < 4; ++i) {
      afH[i] = *(const short8*)&AsH[wr + i * 16 + l15][kk];
      afL[i] = *(const short8*)&AsL[wr + i * 16 + l15][kk];
    }
#pragma unroll
    for (int j = 0; j < 4; ++j) {
      bfH[j] = *(const short8*)&BsH[wc + j * 16 + l15][kk];
      bfL[j] = *(const short8*)&BsL[wc + j * 16 + l15][kk];
    }
#pragma unroll
    for (int i = 0; i < 4; ++i)
#pragma unroll
      for (int j = 0; j < 4; ++j) {
        acc[i][j] = __builtin_amdgcn_mfma_f32_16x16x32_bf16(afH[i], bfH[j], acc[i][j], 0, 0, 0);
        acc[i][j] = __builtin_amdgcn_mfma_f32_16x16x32_bf16(afL[i], bfH[j], acc[i][j], 0, 0, 0);
        acc[i][j] = __builtin_amdgcn_mfma_f32_16x16x32_bf16(afH[i], bfL[j], acc[i][j], 0, 0, 0);
      }
    __syncthreads();
  }

  const int rbase = (lane >> 4) * 4;
#pragma unroll
  for (int j = 0; j < 4; ++j) {
    const int col = bn + wc + j * 16 + l15;
#pragma unroll
    for (int i = 0; i < 4; ++i)
#pragma unroll
      for (int r = 0; r < 4; ++r)
        C[(size_t)(bm + wr + i * 16 + rbase + r) * DIMV + col] = f2b(acc[i][j][r]);
  }
}

// ---------- row transform: mobius_matvec tail + kappa_relu (bf16 msrc, precomputed ||x||^2) ----------
template <bool BFDST>
__global__ __launch_bounds__(256) void rowtrans_kernel(const ushort_t* __restrict__ msrc,
                                                       const float* __restrict__ rowsq,
                                                       void* __restrict__ dstv,
                                                       float* __restrict__ denom) {
  __shared__ float red[4];
  __shared__ float orow[DIMV];
  const int row = blockIdx.x;
  const int t = threadIdx.x;
  uint2 mraw = ((const uint2*)(msrc + (size_t)row * DIMV))[t];
  ushort_t* mh = (ushort_t*)&mraw;
  float4 m4 = make_float4(b2f(mh[0]), b2f(mh[1]), b2f(mh[2]), b2f(mh[3]));
  float sm = m4.x * m4.x + m4.y * m4.y + m4.z * m4.z + m4.w * m4.w;
  sm = blockReduceSum(sm, red);
  float sx = rowsq[row];

  float xn = fmaxf(sqrtf(sx), 1e-15f);
  float mxn = fmaxf(sqrtf(sm), 1e-15f);
  float cx = fminf(xn, 1.0f - 1e-7f);
  float t1 = tanhf(mxn / xn * atanhf(cx));
  float s1 = t1 / mxn;

  float yn = fmaxf(fabsf(t1), 1e-15f);
  float a = atanhf(fminf(yn, 1.0f - 1e-7f)) / yn;
  float k1 = a * s1;
  float4 u = make_float4(fmaxf(k1 * m4.x, 0.0f), fmaxf(k1 * m4.y, 0.0f),
                         fmaxf(k1 * m4.z, 0.0f), fmaxf(k1 * m4.w, 0.0f));
  float su = u.x * u.x + u.y * u.y + u.z * u.z + u.w * u.w;
  su = blockReduceSum(su, red);

  float un = fmaxf(sqrtf(su), 1e-15f);
  float t2 = tanhf(un);
  float s2 = t2 / un;
  if (t2 > 0.996f) s2 *= 0.996f / t2;
  float4 o = make_float4(s2 * u.x, s2 * u.y, s2 * u.z, s2 * u.w);
  if (BFDST) {
    ushort_t h[4] = {f2b(o.x), f2b(o.y), f2b(o.z), f2b(o.w)};
    ((uint2*)((ushort_t*)dstv + (size_t)row * DIMV))[t] = *(uint2*)h;
  } else {
    ((float4*)((float*)dstv + (size_t)row * DIMV))[t] = o;
  }

  if (denom) {
    ((float4*)orow)[t] = o;
    __syncthreads();
    if (t < NHEADS) {
      float s = 0.0f;
#pragma unroll
      for (int i = 0; i < HEADD; ++i) {
        float v = orow[t * HEADD + i];
        s = fmaf(v, v, s);
      }
      denom[t * N_NODES + row] = fmaxf(1.0f - s, 1e-15f);
    }
  }
}

// ---------- ctxT[h][e][d] = sum_n v2[h,n,d] * (gamma/den * mask * V)[h,n,e]  (v2,V bf16) ----------
__global__ __launch_bounds__(256) void context_kernel(const ushort_t* __restrict__ v2buf,
                                                      const ushort_t* __restrict__ vbuf,
                                                      const float* __restrict__ denom,
                                                      const float* __restrict__ mask,
                                                      float* __restrict__ ctxT) {
  __shared__ float s2[64][65];
  __shared__ float sx[64][65];
  const int h = blockIdx.y;
  const int t = threadIdx.x;
  const int d0 = (t >> 4) * 4;
  const int e0 = (t & 15) * 4;
  float acc[4][4];
#pragma unroll
  for (int i = 0; i < 4; ++i)
#pragma unroll
    for (int j = 0; j < 4; ++j) acc[i][j] = 0.0f;

  const int rbase = blockIdx.x * 1024;
  for (int c = 0; c < 16; ++c) {
#pragma unroll
    for (int i = 0; i < 4; ++i) {
      int f = i * 256 + t;
      int r = f >> 4;
      int cc = (f & 15) * 4;
      int row = rbase + c * 64 + r;
      uint2 araw = *(const uint2*)(v2buf + (size_t)row * DIMV + h * HEADD + cc);
      ushort_t* ah = (ushort_t*)&araw;
      s2[r][cc + 0] = b2f(ah[0]); s2[r][cc + 1] = b2f(ah[1]);
      s2[r][cc + 2] = b2f(ah[2]); s2[r][cc + 3] = b2f(ah[3]);
      float dp = denom[(size_t)h * N_NODES + row];
      float gamma = 2.0f / dp;
      float den = clampabs(gamma - 1.0f, 1e-10f);
      float c1 = gamma / den * mask[row];
      uint2 braw = *(const uint2*)(vbuf + (size_t)row * DIMV + h * HEADD + cc);
      ushort_t* bh = (ushort_t*)&braw;
      sx[r][cc + 0] = c1 * b2f(bh[0]); sx[r][cc + 1] = c1 * b2f(bh[1]);
      sx[r][cc + 2] = c1 * b2f(bh[2]); sx[r][cc + 3] = c1 * b2f(bh[3]);
    }
    __syncthreads();
    for (int r = 0; r < 64; ++r) {
      float av[4], bv[4];
#pragma unroll
      for (int i = 0; i < 4; ++i) av[i] = s2[r][d0 + i];
#pragma unroll
      for (int j = 0; j < 4; ++j) bv[j] = sx[r][e0 + j];
#pragma unroll
      for (int i = 0; i < 4; ++i)
#pragma unroll
        for (int j = 0; j < 4; ++j) acc[i][j] = fmaf(av[i], bv[j], acc[i][j]);
    }
    __syncthreads();
  }
#pragma unroll
  for (int i = 0; i < 4; ++i)
#pragma unroll
    for (int j = 0; j < 4; ++j)
      atomicAdd(&ctxT[h * 4096 + (e0 + j) * 64 + (d0 + i)], acc[i][j]);
}

// ---------- out (MFMA): [out|D] = v1 @ [ctx|v2sum]; tail; emit combHi/Lo + rownorm atomics ----------
// A-fragments straight from global v1bf; B in small LDS. 256 rows x 1 head per block.
__global__ __launch_bounds__(256) void out_mfma_kernel(const ushort_t* __restrict__ v1bf,
                                                       const float* __restrict__ v2sum,
                                                       const float* __restrict__ ctxT,
                                                       ushort_t* __restrict__ combHi,
                                                       ushort_t* __restrict__ combLo,
                                                       float* __restrict__ combnorm) {
  __shared__ ushort_t Blds[80][88];
  const int h = blockIdx.y;
  const int bm = blockIdx.x * 256;
  const int t = threadIdx.x;
  const int w = t >> 6, lane = t & 63, l15 = lane & 15;
  const int kk = (lane >> 4) * 8;

  for (int idx = t; idx < 80 * 64; idx += 256) {
    int e = idx >> 6, d = idx & 63;
    float v = 0.0f;
    if (e < 64) v = ctxT[h * 4096 + e * 64 + d];
    else if (e == 64) v = v2sum[h * 64 + d];
    Blds[e][d] = f2b(v);
  }
  __syncthreads();

  f32x4 acc[4][5];
#pragma unroll
  for (int i = 0; i < 4; ++i)
#pragma unroll
    for (int j = 0; j < 5; ++j) acc[i][j] = (f32x4){0.f, 0.f, 0.f, 0.f};
#pragma unroll
  for (int ks = 0; ks < 2; ++ks) {
    short8 bfr[5];
#pragma unroll
    for (int j = 0; j < 5; ++j) bfr[j] = *(const short8*)&Blds[j * 16 + l15][ks * 32 + kk];
#pragma unroll
    for (int i = 0; i < 4; ++i) {
      short8 af = *(const short8*)(v1bf + (size_t)(bm + w * 64 + i * 16 + l15) * DIMV +
                                   h * HEADD + ks * 32 + kk);
#pragma unroll
      for (int j = 0; j < 5; ++j)
        acc[i][j] = __builtin_amdgcn_mfma_f32_16x16x32_bf16(af, bfr[j], acc[i][j], 0, 0, 0);
    }
  }

  const int g4 = (lane >> 4) * 4;
#pragma unroll
  for (int i = 0; i < 4; ++i) {
#pragma unroll
    for (int r = 0; r < 4; ++r) {
      const int row = bm + w * 64 + i * 16 + g4 + r;
      float D = __shfl(acc[i][4][r], lane & 48);
      float Dinv = 1.0f / (D == 0.0f ? 1e-5f : D);
      float o[4];
      float s = 0.0f;
#pragma unroll
      for (int j = 0; j < 4; ++j) {
        o[j] = acc[i][j][r] * Dinv;
        s = fmaf(o[j], o[j], s);
      }
      s += __shfl_xor(s, 1); s += __shfl_xor(s, 2);
      s += __shfl_xor(s, 4); s += __shfl_xor(s, 8);
      float n1 = fmaxf(sqrtf(s), 1e-15f);
      float sc = 1.0f;
      if (n1 > 0.996f) sc = 0.996f / n1;
      float xn = fmaxf(fminf(n1, 0.996f), 1e-15f);
      float cx = fminf(xn, 1.0f - 1e-7f);
      float t2 = tanhf(0.5f * atanhf(cx));
      sc *= t2 / xn;
      if (t2 > 0.996f) sc *= 0.996f / t2;
      if (l15 == 0) atomicAdd(&combnorm[row], s * sc * sc);
#pragma unroll
      for (int j = 0; j < 4; ++j) {
        float ov = o[j] * sc;
        size_t off = (size_t)row * DIMV + h * HEADD + j * 16 + l15;
        ushort_t hi = f2b(ov);
        combHi[off] = hi;
        combLo[off] = f2b(ov - b2f(hi));
      }
    }
  }
}

// ---------- launch ----------

extern "C" void kernel_launch(void* const* d_in, const int* in_sizes, int n_in,
                              void* d_out, int out_size, void* d_ws, size_t ws_size,
                              hipStream_t stream) {
  const float* X = (const float*)d_in[0];
  const float* mask = (const float*)d_in[1];
  const float* Wq = (const float*)d_in[2];
  const float* bq = (const float*)d_in[3];
  const float* Wk = (const float*)d_in[4];
  const float* bk = (const float*)d_in[5];
  const float* Wv = (const float*)d_in[6];
  const float* Wff = (const float*)d_in[7];
  float* out = (float*)d_out;

  const size_t MAT = (size_t)N_NODES * DIMV;
  char* p = (char*)d_ws;
  // R1 (64MB): first half v1bf (Q epi out); second half mxV bf16, later combnorm
  ushort_t* v1bf = (ushort_t*)p;
  ushort_t* mxV = (ushort_t*)(p + MAT * 2);
  float* combnorm = (float*)(p + MAT * 2);
  p += MAT * 4;
  // R2 (64MB): xnormsq (early) / v2bf (K epi out) / combHi+combLo (after context)
  float* xnormsq = (float*)p;
  ushort_t* v2bf = (ushort_t*)p;
  ushort_t* combHi = (ushort_t*)p;
  ushort_t* combLo = combHi + MAT;
  p += MAT * 4;
  // R3 (32MB): Vbf; later WffHi/WffLo
  ushort_t* Vbf = (ushort_t*)p;
  ushort_t* WffHi = Vbf;
  ushort_t* WffLo = Vbf + (size_t)DIMV * DIMV;
  p += MAT * 2;
  // R4 (32MB): Xbf; later outBf (split3 out)
  ushort_t* Xbf = (ushort_t*)p;
  ushort_t* outBf = Xbf;
  p += MAT * 2;
  float* denom = (float*)p;  p += (size_t)NHEADS * N_NODES * 4;
  float* v2sum = (float*)p;  p += 1024 * 4;
  float* ctxT = (float*)p;   p += (size_t)NHEADS * 4096 * 4;
  const size_t need = (size_t)(p - (char*)d_ws);
  if (ws_size < need) return;

  ushort_t* Wt = (ushort_t*)d_out;  // 2MB scratch inside d_out (free until final rowtrans)

  dim3 tgrid(32, 32);
  dim3 ggrid(DIMV / 128, N_NODES / 128);

  cvt_norm_kernel<<<N_NODES, 256, 0, stream>>>(X, Xbf, xnormsq);
  // V path: mxV bf16, then rowtrans -> Vbf + denom
  transW_kernel<false><<<tgrid, 256, 0, stream>>>(Wv, Wt, nullptr);
  gemm_bf<0><<<ggrid, 256, 0, stream>>>(Xbf, Wt, nullptr, nullptr, nullptr, nullptr, mxV);
  rowtrans_kernel<true><<<N_NODES, 256, 0, stream>>>(mxV, xnormsq, Vbf, denom);
  // zero accumulators (v2sum+ctxT contiguous; combnorm after mxV is dead)
  hipMemsetAsync(v2sum, 0, (1024 + 4096 * NHEADS) * sizeof(float), stream);
  hipMemsetAsync(combnorm, 0, N_NODES * sizeof(float), stream);
  // K path: fused v2 + v2sum
  transW_kernel<false><<<tgrid, 256, 0, stream>>>(Wk, Wt, nullptr);
  gemm_bf<2><<<ggrid, 256, 0, stream>>>(Xbf, Wt, bk, denom, mask, v2sum, v2bf);
  // context (transposed output)
  context_kernel<<<dim3(16, NHEADS), 256, 0, stream>>>(v2bf, Vbf, denom, mask, ctxT);
  // Q path: fused v1
  transW_kernel<false><<<tgrid, 256, 0, stream>>>(Wq, Wt, nullptr);
  gemm_bf<1><<<ggrid, 256, 0, stream>>>(Xbf, Wt, bq, denom, nullptr, nullptr, v1bf);
  // attention out -> combHi/Lo + row norms
  out_mfma_kernel<<<dim3(N_NODES / 256, NHEADS), 256, 0, stream>>>(v1bf, v2sum, ctxT, combHi,
                                                                   combLo, combnorm);
  // final: fused 3-term split GEMM -> outBf, then rowtrans -> d_out
  transW_kernel<true><<<tgrid, 256, 0, stream>>>(Wff, WffHi, WffLo);
  gemm_split3<<<ggrid, 256, 0, stream>>>(combHi, combLo, WffHi, WffLo, outBf);
  rowtrans_kernel<false><<<N_NODES, 256, 0, stream>>>(outBf, combnorm, out, nullptr);
}

// Round 5
// 528.682 us; speedup vs baseline: 3.7695x; 1.1449x over previous
//
#include <hip/hip_runtime.h>
#include <hip/hip_bf16.h>
#include <math.h>

#define N_NODES 16384
#define DIMV 1024
#define NHEADS 16
#define HEADD 64

typedef __attribute__((ext_vector_type(8))) short short8;
typedef __attribute__((ext_vector_type(4))) float f32x4;
typedef unsigned short ushort_t;

// async global->LDS, 16B per lane; LDS dest is wave-uniform base + lane*16
#define GLD16(gptr, lptr)                                                                 \
  __builtin_amdgcn_global_load_lds((const __attribute__((address_space(1))) void*)(gptr), \
                                   (__attribute__((address_space(3))) void*)(lptr), 16, 0, 0)

// ---------- helpers ----------

__device__ __forceinline__ float waveReduceSum(float v) {
#pragma unroll
  for (int m = 32; m; m >>= 1) v += __shfl_xor(v, m);
  return v;
}

__device__ __forceinline__ float blockReduceSum(float v, float* red) {
  float w = waveReduceSum(v);
  __syncthreads();
  if ((threadIdx.x & 63) == 0) red[threadIdx.x >> 6] = w;
  __syncthreads();
  return red[0] + red[1] + red[2] + red[3];
}

__device__ __forceinline__ float elup1(float z) {
  return z > 0.0f ? z + 1.0f : expm1f(z) + 1.0f;
}

__device__ __forceinline__ float clampabs(float x, float eps) {
  float s = (x >= 0.0f) ? 1.0f : -1.0f;
  return s * fmaxf(fabsf(x), eps);
}

// fp32 -> bf16 bits, RNE
__device__ __forceinline__ ushort_t f2b(float x) {
  unsigned u = __float_as_uint(x);
  unsigned r = (u + 0x7FFFu + ((u >> 16) & 1u)) >> 16;
  return (ushort_t)r;
}
__device__ __forceinline__ float b2f(ushort_t h) {
  return __uint_as_float(((unsigned)h) << 16);
}

// ---------- X -> bf16 + row sumsq (one block per row) ----------
__global__ __launch_bounds__(256) void cvt_norm_kernel(const float* __restrict__ src,
                                                       ushort_t* __restrict__ dst,
                                                       float* __restrict__ rowsq) {
  __shared__ float red[4];
  const int row = blockIdx.x;
  const int t = threadIdx.x;
  float4 x4 = ((const float4*)(src + (size_t)row * DIMV))[t];
  ushort_t h[4] = {f2b(x4.x), f2b(x4.y), f2b(x4.z), f2b(x4.w)};
  ((uint2*)(dst + (size_t)row * DIMV))[t] = *(uint2*)h;
  float s = x4.x * x4.x + x4.y * x4.y + x4.z * x4.z + x4.w * x4.w;
  s = blockReduceSum(s, red);
  if (t == 0) rowsq[row] = s;
}

// ---------- weight transpose -> bf16 (hi, and optional lo residual) ----------
template <bool LO>
__global__ __launch_bounds__(256) void transW_kernel(const float* __restrict__ src,
                                                     ushort_t* __restrict__ hi,
                                                     ushort_t* __restrict__ lo) {
  __shared__ float tile[32][33];
  const int bx = blockIdx.x * 32, by = blockIdx.y * 32;
  const int tx = threadIdx.x & 31, ty = threadIdx.x >> 5;
#pragma unroll
  for (int i = 0; i < 32; i += 8) tile[ty + i][tx] = src[(size_t)(by + ty + i) * DIMV + bx + tx];
  __syncthreads();
#pragma unroll
  for (int i = 0; i < 32; i += 8) {
    float v = tile[tx][ty + i];
    ushort_t h = f2b(v);
    hi[(size_t)(bx + ty + i) * DIMV + by + tx] = h;
    if (LO) lo[(size_t)(bx + ty + i) * DIMV + by + tx] = f2b(v - b2f(h));
  }
}

// ---------- bf16 MFMA GEMM, BK=32 (r3-proven geometry), XCD swizzle, fused epilogues ----
// A: [M][1024] bf16, Bt: [NB*128 n][1024 k] bf16. 128x128 tile, 4 waves 2x2, 4x4 frags.
// EPI 0: Cq = bf16(acc)                                  (V path)
// EPI 3: cols < 1024 -> Cq = bf16(v1); cols >= 1024 -> Ck = bf16(v2), v2sum atomics (QK fused)
template <int EPI, int NB>
__global__ __launch_bounds__(256) void gemm_bf(const ushort_t* __restrict__ A,
                                               const ushort_t* __restrict__ Bt,
                                               const float* __restrict__ biasQ,
                                               const float* __restrict__ biasK,
                                               const float* __restrict__ denom,
                                               const float* __restrict__ mask,
                                               float* __restrict__ v2sum,
                                               ushort_t* __restrict__ Cq,
                                               ushort_t* __restrict__ Ck) {
  __shared__ ushort_t As[128][32];
  __shared__ ushort_t Bs[128][32];
  // XCD-aware swizzle: nwg = NB*128 (divisible by 8); each XCD gets a contiguous swz range,
  // col-tile fastest -> B stays L2-resident per XCD, A panels fetched ~once device-wide.
  const int bid = blockIdx.x;
  const int swz = (bid & 7) * (NB * 16) + (bid >> 3);
  const int bm = (swz / NB) * 128;
  const int bn = (swz & (NB - 1)) * 128;
  const int t = threadIdx.x;
  const int w = t >> 6, lane = t & 63, l15 = lane & 15;
  const int wr = (w >> 1) * 64, wc = (w & 1) * 64;
  const int kk = (lane >> 4) * 8;

  // two 1KB chunks per wave per operand: chunk c covers lane-linear idx c*64+lane,
  // LDS byte = idx*16 = row*64 + col*2  (row = idx>>2, col = (idx&3)*8)
  const int c0 = w, c1 = 4 + w;
  const int x0 = c0 * 64 + lane, x1 = c1 * 64 + lane;
  const ushort_t* gA0 = A + (size_t)(bm + (x0 >> 2)) * DIMV + (x0 & 3) * 8;
  const ushort_t* gA1 = A + (size_t)(bm + (x1 >> 2)) * DIMV + (x1 & 3) * 8;
  const ushort_t* gB0 = Bt + (size_t)(bn + (x0 >> 2)) * DIMV + (x0 & 3) * 8;
  const ushort_t* gB1 = Bt + (size_t)(bn + (x1 >> 2)) * DIMV + (x1 & 3) * 8;
  ushort_t* lA0 = &As[0][0] + c0 * 512;
  ushort_t* lA1 = &As[0][0] + c1 * 512;
  ushort_t* lB0 = &Bs[0][0] + c0 * 512;
  ushort_t* lB1 = &Bs[0][0] + c1 * 512;

  f32x4 acc[4][4];
#pragma unroll
  for (int i = 0; i < 4; ++i)
#pragma unroll
    for (int j = 0; j < 4; ++j) acc[i][j] = (f32x4){0.f, 0.f, 0.f, 0.f};

  for (int k0 = 0; k0 < DIMV; k0 += 32) {
    GLD16(gA0 + k0, lA0);
    GLD16(gA1 + k0, lA1);
    GLD16(gB0 + k0, lB0);
    GLD16(gB1 + k0, lB1);
    __syncthreads();
    short8 af[4], bf[4];
#pragma unroll
    for (int i = 0; i < 4; ++i) af[i] = *(const short8*)&As[wr + i * 16 + l15][kk];
#pragma unroll
    for (int j = 0; j < 4; ++j) bf[j] = *(const short8*)&Bs[wc + j * 16 + l15][kk];
#pragma unroll
    for (int i = 0; i < 4; ++i)
#pragma unroll
      for (int j = 0; j < 4; ++j)
        acc[i][j] = __builtin_amdgcn_mfma_f32_16x16x32_bf16(af[i], bf[j], acc[i][j], 0, 0, 0);
    __syncthreads();
  }

  // epilogue. C/D layout: col = lane&15, row = (lane>>4)*4 + r
  const int rbase = (lane >> 4) * 4;
  if (EPI == 0) {
#pragma unroll
    for (int j = 0; j < 4; ++j) {
      const int col = bn + wc + j * 16 + l15;
#pragma unroll
      for (int i = 0; i < 4; ++i)
#pragma unroll
        for (int r = 0; r < 4; ++r)
          Cq[(size_t)(bm + wr + i * 16 + rbase + r) * DIMV + col] = f2b(acc[i][j][r]);
    }
  } else {
    const bool isK = (bn >= DIMV);  // block-uniform
    const int h = ((bn + wc) >> 6) & (NHEADS - 1);
    int lc[4];
    float bb[4];
#pragma unroll
    for (int j = 0; j < 4; ++j) {
      lc[j] = (bn + wc + j * 16 + l15) & (DIMV - 1);
      bb[j] = isK ? biasK[lc[j]] : biasQ[lc[j]];
    }
    float csum[4] = {0.f, 0.f, 0.f, 0.f};
#pragma unroll
    for (int i = 0; i < 4; ++i) {
#pragma unroll
      for (int r = 0; r < 4; ++r) {
        const int row = bm + wr + i * 16 + rbase + r;
        const float invdp = 1.0f / denom[(size_t)h * N_NODES + row];
        float den = 0.f, mk = 0.f;
        if (isK) {
          den = clampabs(2.0f * invdp - 1.0f, 1e-10f);
          mk = mask[row];
        }
#pragma unroll
        for (int j = 0; j < 4; ++j) {
          float val = elup1((acc[i][j][r] + bb[j]) * invdp);
          if (isK) {
            val = den * val * mk;
            csum[j] += val;
            Ck[(size_t)row * DIMV + lc[j]] = f2b(val);
          } else {
            Cq[(size_t)row * DIMV + lc[j]] = f2b(val);
          }
        }
      }
    }
    if (isK) {
#pragma unroll
      for (int j = 0; j < 4; ++j) atomicAdd(&v2sum[lc[j]], csum[j]);
    }
  }
}

// ---------- fused 3-term split GEMM: C = bf16(AhiBhi + AloBhi + AhiBlo), BK=32, swizzled ----------
__global__ __launch_bounds__(256) void gemm_split3(const ushort_t* __restrict__ Ahi,
                                                   const ushort_t* __restrict__ Alo,
                                                   const ushort_t* __restrict__ Bhi,
                                                   const ushort_t* __restrict__ Blo,
                                                   ushort_t* __restrict__ C) {
  __shared__ ushort_t AsH[128][32], AsL[128][32], BsH[128][32], BsL[128][32];
  const int bid = blockIdx.x;
  const int swz = (bid & 7) * 128 + (bid >> 3);  // nwg = 1024
  const int bm = (swz >> 3) * 128;
  const int bn = (swz & 7) * 128;
  const int t = threadIdx.x;
  const int w = t >> 6, lane = t & 63, l15 = lane & 15;
  const int wr = (w >> 1) * 64, wc = (w & 1) * 64;
  const int kk = (lane >> 4) * 8;

  const int c0 = w, c1 = 4 + w;
  const int x0 = c0 * 64 + lane, x1 = c1 * 64 + lane;
  const size_t go0A = (size_t)(bm + (x0 >> 2)) * DIMV + (x0 & 3) * 8;
  const size_t go1A = (size_t)(bm + (x1 >> 2)) * DIMV + (x1 & 3) * 8;
  const size_t go0B = (size_t)(bn + (x0 >> 2)) * DIMV + (x0 & 3) * 8;
  const size_t go1B = (size_t)(bn + (x1 >> 2)) * DIMV + (x1 & 3) * 8;
  ushort_t* lh0A = &AsH[0][0] + c0 * 512;
  ushort_t* lh1A = &AsH[0][0] + c1 * 512;
  ushort_t* ll0A = &AsL[0][0] + c0 * 512;
  ushort_t* ll1A = &AsL[0][0] + c1 * 512;
  ushort_t* lh0B = &BsH[0][0] + c0 * 512;
  ushort_t* lh1B = &BsH[0][0] + c1 * 512;
  ushort_t* ll0B = &BsL[0][0] + c0 * 512;
  ushort_t* ll1B = &BsL[0][0] + c1 * 512;

  f32x4 acc[4][4];
#pragma unroll
  for (int i = 0; i < 4; ++i)
#pragma unroll
    for (int j = 0; j < 4; ++j) acc[i][j] = (f32x4){0.f, 0.f, 0.f, 0.f};

  for (int k0 = 0; k0 < DIMV; k0 += 32) {
    GLD16(Ahi + go0A + k0, lh0A);
    GLD16(Ahi + go1A + k0, lh1A);
    GLD16(Alo + go0A + k0, ll0A);
    GLD16(Alo + go1A + k0, ll1A);
    GLD16(Bhi + go0B + k0, lh0B);
    GLD16(Bhi + go1B + k0, lh1B);
    GLD16(Blo + go0B + k0, ll0B);
    GLD16(Blo + go1B + k0, ll1B);
    __syncthreads();
    short8 afH[4], afL[4], bfH[4], bfL[4];
#pragma unroll
    for (int i = 0; i < 4; ++i) {
      afH[i] = *(const short8*)&AsH[wr + i * 16 + l15][kk];
      afL[i] = *(const short8*)&AsL[wr + i * 16 + l15][kk];
    }
#pragma unroll
    for (int j = 0; j < 4; ++j) {
      bfH[j] = *(const short8*)&BsH[wc + j * 16 + l15][kk];
      bfL[j] = *(const short8*)&BsL[wc + j * 16 + l15][kk];
    }
#pragma unroll
    for (int i = 0; i < 4; ++i)
#pragma unroll
      for (int j = 0; j < 4; ++j) {
        acc[i][j] = __builtin_amdgcn_mfma_f32_16x16x32_bf16(afH[i], bfH[j], acc[i][j], 0, 0, 0);
        acc[i][j] = __builtin_amdgcn_mfma_f32_16x16x32_bf16(afL[i], bfH[j], acc[i][j], 0, 0, 0);
        acc[i][j] = __builtin_amdgcn_mfma_f32_16x16x32_bf16(afH[i], bfL[j], acc[i][j], 0, 0, 0);
      }
    __syncthreads();
  }

  const int rbase = (lane >> 4) * 4;
#pragma unroll
  for (int j = 0; j < 4; ++j) {
    const int col = bn + wc + j * 16 + l15;
#pragma unroll
    for (int i = 0; i < 4; ++i)
#pragma unroll
      for (int r = 0; r < 4; ++r)
        C[(size_t)(bm + wr + i * 16 + rbase + r) * DIMV + col] = f2b(acc[i][j][r]);
  }
}

// ---------- row transform: mobius_matvec tail + kappa_relu (bf16 msrc, precomputed ||x||^2) ----------
template <bool BFDST>
__global__ __launch_bounds__(256) void rowtrans_kernel(const ushort_t* __restrict__ msrc,
                                                       const float* __restrict__ rowsq,
                                                       void* __restrict__ dstv,
                                                       float* __restrict__ denom) {
  __shared__ float red[4];
  __shared__ float orow[DIMV];
  const int row = blockIdx.x;
  const int t = threadIdx.x;
  uint2 mraw = ((const uint2*)(msrc + (size_t)row * DIMV))[t];
  ushort_t* mh = (ushort_t*)&mraw;
  float4 m4 = make_float4(b2f(mh[0]), b2f(mh[1]), b2f(mh[2]), b2f(mh[3]));
  float sm = m4.x * m4.x + m4.y * m4.y + m4.z * m4.z + m4.w * m4.w;
  sm = blockReduceSum(sm, red);
  float sx = rowsq[row];

  float xn = fmaxf(sqrtf(sx), 1e-15f);
  float mxn = fmaxf(sqrtf(sm), 1e-15f);
  float cx = fminf(xn, 1.0f - 1e-7f);
  float t1 = tanhf(mxn / xn * atanhf(cx));
  float s1 = t1 / mxn;

  float yn = fmaxf(fabsf(t1), 1e-15f);
  float a = atanhf(fminf(yn, 1.0f - 1e-7f)) / yn;
  float k1 = a * s1;
  float4 u = make_float4(fmaxf(k1 * m4.x, 0.0f), fmaxf(k1 * m4.y, 0.0f),
                         fmaxf(k1 * m4.z, 0.0f), fmaxf(k1 * m4.w, 0.0f));
  float su = u.x * u.x + u.y * u.y + u.z * u.z + u.w * u.w;
  su = blockReduceSum(su, red);

  float un = fmaxf(sqrtf(su), 1e-15f);
  float t2 = tanhf(un);
  float s2 = t2 / un;
  if (t2 > 0.996f) s2 *= 0.996f / t2;
  float4 o = make_float4(s2 * u.x, s2 * u.y, s2 * u.z, s2 * u.w);
  if (BFDST) {
    ushort_t h[4] = {f2b(o.x), f2b(o.y), f2b(o.z), f2b(o.w)};
    ((uint2*)((ushort_t*)dstv + (size_t)row * DIMV))[t] = *(uint2*)h;
  } else {
    ((float4*)((float*)dstv + (size_t)row * DIMV))[t] = o;
  }

  if (denom) {
    ((float4*)orow)[t] = o;
    __syncthreads();
    if (t < NHEADS) {
      float s = 0.0f;
#pragma unroll
      for (int i = 0; i < HEADD; ++i) {
        float v = orow[t * HEADD + i];
        s = fmaf(v, v, s);
      }
      denom[t * N_NODES + row] = fmaxf(1.0f - s, 1e-15f);
    }
  }
}

// ---------- ctxT[h][e][d] = sum_n v2[h,n,d] * (gamma/den * mask * V)[h,n,e]  (v2,V bf16) ----------
__global__ __launch_bounds__(256) void context_kernel(const ushort_t* __restrict__ v2buf,
                                                      const ushort_t* __restrict__ vbuf,
                                                      const float* __restrict__ denom,
                                                      const float* __restrict__ mask,
                                                      float* __restrict__ ctxT) {
  __shared__ float s2[64][65];
  __shared__ float sx[64][65];
  const int h = blockIdx.y;
  const int t = threadIdx.x;
  const int d0 = (t >> 4) * 4;
  const int e0 = (t & 15) * 4;
  float acc[4][4];
#pragma unroll
  for (int i = 0; i < 4; ++i)
#pragma unroll
    for (int j = 0; j < 4; ++j) acc[i][j] = 0.0f;

  const int rbase = blockIdx.x * 1024;
  for (int c = 0; c < 16; ++c) {
#pragma unroll
    for (int i = 0; i < 4; ++i) {
      int f = i * 256 + t;
      int r = f >> 4;
      int cc = (f & 15) * 4;
      int row = rbase + c * 64 + r;
      uint2 araw = *(const uint2*)(v2buf + (size_t)row * DIMV + h * HEADD + cc);
      ushort_t* ah = (ushort_t*)&araw;
      s2[r][cc + 0] = b2f(ah[0]); s2[r][cc + 1] = b2f(ah[1]);
      s2[r][cc + 2] = b2f(ah[2]); s2[r][cc + 3] = b2f(ah[3]);
      float dp = denom[(size_t)h * N_NODES + row];
      float gamma = 2.0f / dp;
      float den = clampabs(gamma - 1.0f, 1e-10f);
      float c1 = gamma / den * mask[row];
      uint2 braw = *(const uint2*)(vbuf + (size_t)row * DIMV + h * HEADD + cc);
      ushort_t* bh = (ushort_t*)&braw;
      sx[r][cc + 0] = c1 * b2f(bh[0]); sx[r][cc + 1] = c1 * b2f(bh[1]);
      sx[r][cc + 2] = c1 * b2f(bh[2]); sx[r][cc + 3] = c1 * b2f(bh[3]);
    }
    __syncthreads();
    for (int r = 0; r < 64; ++r) {
      float av[4], bv[4];
#pragma unroll
      for (int i = 0; i < 4; ++i) av[i] = s2[r][d0 + i];
#pragma unroll
      for (int j = 0; j < 4; ++j) bv[j] = sx[r][e0 + j];
#pragma unroll
      for (int i = 0; i < 4; ++i)
#pragma unroll
        for (int j = 0; j < 4; ++j) acc[i][j] = fmaf(av[i], bv[j], acc[i][j]);
    }
    __syncthreads();
  }
#pragma unroll
  for (int i = 0; i < 4; ++i)
#pragma unroll
    for (int j = 0; j < 4; ++j)
      atomicAdd(&ctxT[h * 4096 + (e0 + j) * 64 + (d0 + i)], acc[i][j]);
}

// ---------- out (MFMA): [out|D] = v1 @ [ctx|v2sum]; tail; emit combHi/Lo + rownorm atomics ----------
__global__ __launch_bounds__(256) void out_mfma_kernel(const ushort_t* __restrict__ v1bf,
                                                       const float* __restrict__ v2sum,
                                                       const float* __restrict__ ctxT,
                                                       ushort_t* __restrict__ combHi,
                                                       ushort_t* __restrict__ combLo,
                                                       float* __restrict__ combnorm) {
  __shared__ ushort_t Blds[80][88];
  const int h = blockIdx.y;
  const int bm = blockIdx.x * 256;
  const int t = threadIdx.x;
  const int w = t >> 6, lane = t & 63, l15 = lane & 15;
  const int kk = (lane >> 4) * 8;

  for (int idx = t; idx < 80 * 64; idx += 256) {
    int e = idx >> 6, d = idx & 63;
    float v = 0.0f;
    if (e < 64) v = ctxT[h * 4096 + e * 64 + d];
    else if (e == 64) v = v2sum[h * 64 + d];
    Blds[e][d] = f2b(v);
  }
  __syncthreads();

  f32x4 acc[4][5];
#pragma unroll
  for (int i = 0; i < 4; ++i)
#pragma unroll
    for (int j = 0; j < 5; ++j) acc[i][j] = (f32x4){0.f, 0.f, 0.f, 0.f};
#pragma unroll
  for (int ks = 0; ks < 2; ++ks) {
    short8 bfr[5];
#pragma unroll
    for (int j = 0; j < 5; ++j) bfr[j] = *(const short8*)&Blds[j * 16 + l15][ks * 32 + kk];
#pragma unroll
    for (int i = 0; i < 4; ++i) {
      short8 af = *(const short8*)(v1bf + (size_t)(bm + w * 64 + i * 16 + l15) * DIMV +
                                   h * HEADD + ks * 32 + kk);
#pragma unroll
      for (int j = 0; j < 5; ++j)
        acc[i][j] = __builtin_amdgcn_mfma_f32_16x16x32_bf16(af, bfr[j], acc[i][j], 0, 0, 0);
    }
  }

  const int g4 = (lane >> 4) * 4;
#pragma unroll
  for (int i = 0; i < 4; ++i) {
#pragma unroll
    for (int r = 0; r < 4; ++r) {
      const int row = bm + w * 64 + i * 16 + g4 + r;
      float D = __shfl(acc[i][4][r], lane & 48);
      float Dinv = 1.0f / (D == 0.0f ? 1e-5f : D);
      float o[4];
      float s = 0.0f;
#pragma unroll
      for (int j = 0; j < 4; ++j) {
        o[j] = acc[i][j][r] * Dinv;
        s = fmaf(o[j], o[j], s);
      }
      s += __shfl_xor(s, 1); s += __shfl_xor(s, 2);
      s += __shfl_xor(s, 4); s += __shfl_xor(s, 8);
      float n1 = fmaxf(sqrtf(s), 1e-15f);
      float sc = 1.0f;
      if (n1 > 0.996f) sc = 0.996f / n1;
      float xn = fmaxf(fminf(n1, 0.996f), 1e-15f);
      float cx = fminf(xn, 1.0f - 1e-7f);
      float t2 = tanhf(0.5f * atanhf(cx));
      sc *= t2 / xn;
      if (t2 > 0.996f) sc *= 0.996f / t2;
      if (l15 == 0) atomicAdd(&combnorm[row], s * sc * sc);
#pragma unroll
      for (int j = 0; j < 4; ++j) {
        float ov = o[j] * sc;
        size_t off = (size_t)row * DIMV + h * HEADD + j * 16 + l15;
        ushort_t hi = f2b(ov);
        combHi[off] = hi;
        combLo[off] = f2b(ov - b2f(hi));
      }
    }
  }
}

// ---------- launch ----------

extern "C" void kernel_launch(void* const* d_in, const int* in_sizes, int n_in,
                              void* d_out, int out_size, void* d_ws, size_t ws_size,
                              hipStream_t stream) {
  const float* X = (const float*)d_in[0];
  const float* mask = (const float*)d_in[1];
  const float* Wq = (const float*)d_in[2];
  const float* bq = (const float*)d_in[3];
  const float* Wk = (const float*)d_in[4];
  const float* bk = (const float*)d_in[5];
  const float* Wv = (const float*)d_in[6];
  const float* Wff = (const float*)d_in[7];
  float* out = (float*)d_out;

  const size_t MAT = (size_t)N_NODES * DIMV;
  char* p = (char*)d_ws;
  // R1 (64MB): first half v1bf (QK epi out); second half mxV bf16, later combnorm
  ushort_t* v1bf = (ushort_t*)p;
  ushort_t* mxV = (ushort_t*)(p + MAT * 2);
  float* combnorm = (float*)(p + MAT * 2);
  p += MAT * 4;
  // R2 (64MB): xnormsq (early) / v2bf (QK epi out) / combHi+combLo (after context)
  float* xnormsq = (float*)p;
  ushort_t* v2bf = (ushort_t*)p;
  ushort_t* combHi = (ushort_t*)p;
  ushort_t* combLo = combHi + MAT;
  p += MAT * 4;
  // R3 (32MB): Vbf; later WffHi/WffLo
  ushort_t* Vbf = (ushort_t*)p;
  ushort_t* WffHi = Vbf;
  ushort_t* WffLo = Vbf + (size_t)DIMV * DIMV;
  p += MAT * 2;
  // R4 (32MB): Xbf; later outBf (split3 out)
  ushort_t* Xbf = (ushort_t*)p;
  ushort_t* outBf = Xbf;
  p += MAT * 2;
  float* denom = (float*)p;  p += (size_t)NHEADS * N_NODES * 4;
  float* v2sum = (float*)p;  p += 1024 * 4;
  float* ctxT = (float*)p;   p += (size_t)NHEADS * 4096 * 4;
  const size_t need = (size_t)(p - (char*)d_ws);
  if (ws_size < need) return;

  // W^T bf16 scratch inside d_out (free until the final rowtrans writes it):
  ushort_t* Wt = (ushort_t*)d_out;            // Wv^T, later Wq^T (rows 0..1023)
  ushort_t* WtK = Wt + (size_t)DIMV * DIMV;   // Wk^T (rows 1024..2047 of stacked QK)

  dim3 tgrid(32, 32);

  cvt_norm_kernel<<<N_NODES, 256, 0, stream>>>(X, Xbf, xnormsq);
  // V path: mxV bf16, then rowtrans -> Vbf + denom
  transW_kernel<false><<<tgrid, 256, 0, stream>>>(Wv, Wt, nullptr);
  gemm_bf<0, 8><<<1024, 256, 0, stream>>>(Xbf, Wt, nullptr, nullptr, nullptr, nullptr,
                                          nullptr, mxV, nullptr);
  rowtrans_kernel<true><<<N_NODES, 256, 0, stream>>>(mxV, xnormsq, Vbf, denom);
  // zero accumulators (v2sum+ctxT contiguous; combnorm over dead mxV)
  hipMemsetAsync(v2sum, 0, (1024 + 4096 * NHEADS) * sizeof(float), stream);
  hipMemsetAsync(combnorm, 0, N_NODES * sizeof(float), stream);
  // QK fused: stacked [Wq^T; Wk^T], epilogue emits v1 (cols<1024) and v2 + v2sum (cols>=1024)
  transW_kernel<false><<<tgrid, 256, 0, stream>>>(Wq, Wt, nullptr);
  transW_kernel<false><<<tgrid, 256, 0, stream>>>(Wk, WtK, nullptr);
  gemm_bf<3, 16><<<2048, 256, 0, stream>>>(Xbf, Wt, bq, bk, denom, mask, v2sum, v1bf, v2bf);
  // context (transposed output)
  context_kernel<<<dim3(16, NHEADS), 256, 0, stream>>>(v2bf, Vbf, denom, mask, ctxT);
  // attention out -> combHi/Lo + row norms
  out_mfma_kernel<<<dim3(N_NODES / 256, NHEADS), 256, 0, stream>>>(v1bf, v2sum, ctxT, combHi,
                                                                   combLo, combnorm);
  // final: fused 3-term split GEMM -> outBf, then rowtrans -> d_out
  transW_kernel<true><<<tgrid, 256, 0, stream>>>(Wff, WffHi, WffLo);
  gemm_split3<<<1024, 256, 0, stream>>>(combHi, combLo, WffHi, WffLo, outBf);
  rowtrans_kernel<false><<<N_NODES, 256, 0, stream>>>(outBf, combnorm, out, nullptr);
}